// Round 19
// baseline (1179.819 us; speedup 1.0000x reference)
//
#include <hip/hip_runtime.h>

// ---------------- problem constants ----------------
#define N_NODES 50000
#define N_EDGES 800000
#define P_PERT  4
#define NTOT    (P_PERT * N_NODES)   // 200000
#define HDIM    64
#define NGRAPH  512
#define NCLASS  10
#define BN_EPS  1e-5f
#define SCAN_BLOCKS ((N_NODES + 255) / 256)   // 196
#define BN_SLICES 64
#define NBUCKET 64
#define SAH_STRIDE 72  // halves; 144B rows, 16B-aligned frag reads, 2-way bank alias max
#define SC_STRIDE 72   // halves
#define ZERO_FLOATS 297120          // 1188480 bytes zeroed at ws start
#define PSTRIDE ((size_t)(N_NODES + 1) * 32)   // halves per part (+1 zeroed dummy node)
#define GATHER_BLOCKS (((N_NODES + 63) / 64) * 8)  // 782 groups x 8 parts = 6256

typedef _Float16 half4 __attribute__((ext_vector_type(4)));
typedef _Float16 f16x8 __attribute__((ext_vector_type(8)));
typedef float    f32x4 __attribute__((ext_vector_type(4)));
typedef unsigned short u16x8 __attribute__((ext_vector_type(8)));

// R18 VERIFIED R3: 8 XCD-resident hwh partitions, FETCH 188 -> 20.6 MB.
// R19 VERIFIED R5: node-per-lane padded walk 105 -> 57.6 us.
// R20 VERIFIED R11: 16 nodes x 4 flanes, pk tree, csr prefetch -> 46 us.
// R21 VERIFIED R13: slot-split fill (no atomic), wide bn_reduce, run-length
// final_pool -> 441.5 -> 399.9 us; gather_bn (4x46 us) is the only hot kernel.
// R22 (this round): gather waves run lockstep over max-degree of their 16
// nodes (E[max16 Poisson16]~26 vs mean 16 -> ~40% masked iterations).
// Degree-bucket permutation: 3 tiny kernels sort nodes by ceil(deg/8);
// gather indexes perm[] so each wave's nodes need EQUAL iterations.
// Inner loop byte-identical to verified R20.
// R17 lesson: NO device-scope fences in the gather (kills per-XCD L2).
// R13 lesson: 64B node granules, 4096-aligned bases.

// ---------------- CSR build ----------------

// counts AND records each edge's slot within its dst list (atomic return val)
__global__ void count_kernel(const int* __restrict__ ei, int* __restrict__ cnt,
                             int* __restrict__ slot) {
    int j = blockIdx.x * blockDim.x + threadIdx.x;
    if (j >= N_EDGES) return;
    slot[j] = atomicAdd(&cnt[ei[N_EDGES + j]], 1);
}

// scans PADDED counts ((cnt+7)&~7) so every node's list is a multiple of 8;
// dinv still uses the raw count.
__global__ void scan_reduce(const int* __restrict__ cnt, int* __restrict__ bsum,
                            float* __restrict__ dinv) {
    __shared__ int sdata[256];
    int i = blockIdx.x * 256 + threadIdx.x;
    int v = (i < N_NODES) ? cnt[i] : 0;
    if (i < N_NODES) dinv[i] = rsqrtf((float)v + 1.0f);
    sdata[threadIdx.x] = (v + 7) & ~7;
    __syncthreads();
    for (int off = 128; off > 0; off >>= 1) {
        if (threadIdx.x < off) sdata[threadIdx.x] += sdata[threadIdx.x + off];
        __syncthreads();
    }
    if (threadIdx.x == 0) bsum[blockIdx.x] = sdata[0];
}

__global__ void scan_tops(const int* __restrict__ bsum, int* __restrict__ boff,
                          int* __restrict__ rowptr) {
    __shared__ int sdata[256];
    int t = threadIdx.x;
    int v = (t < SCAN_BLOCKS) ? bsum[t] : 0;
    sdata[t] = v;
    __syncthreads();
    for (int off = 1; off < 256; off <<= 1) {
        int tmp = (t >= off) ? sdata[t - off] : 0;
        __syncthreads();
        sdata[t] += tmp;
        __syncthreads();
    }
    if (t < SCAN_BLOCKS) boff[t] = sdata[t] - v;
    if (t == 255) rowptr[N_NODES] = sdata[255];
}

__global__ void scan_write(const int* __restrict__ cnt, const int* __restrict__ boff,
                           int* __restrict__ rowptr) {
    __shared__ int sdata[256];
    int i = blockIdx.x * 256 + threadIdx.x;
    int v = (i < N_NODES) ? ((cnt[i] + 7) & ~7) : 0;
    sdata[threadIdx.x] = v;
    __syncthreads();
    for (int off = 1; off < 256; off <<= 1) {
        int tmp = (threadIdx.x >= off) ? sdata[threadIdx.x - off] : 0;
        __syncthreads();
        sdata[threadIdx.x] += tmp;
        __syncthreads();
    }
    if (i < N_NODES) rowptr[i] = boff[blockIdx.x] + sdata[threadIdx.x] - v;
}

// csr: src index only (ushort). Atomic-free: position from precomputed slot.
__global__ void fill_kernel(const int* __restrict__ ei, const int* __restrict__ rowptr,
                            const int* __restrict__ slot, unsigned short* __restrict__ csr) {
    int j = blockIdx.x * blockDim.x + threadIdx.x;
    if (j >= N_EDGES) return;
    int s = ei[j], d = ei[N_EDGES + j];
    csr[rowptr[d] + slot[j]] = (unsigned short)s;
}

// fill pad slots [cnt, (cnt+7)&~7) with the dummy node index (zeroed record)
__global__ void pad_kernel(const int* __restrict__ cnt, const int* __restrict__ rowptr,
                           unsigned short* __restrict__ csr) {
    int v = blockIdx.x * 256 + threadIdx.x;
    if (v >= N_NODES) return;
    int c = cnt[v], cp = (c + 7) & ~7, base = rowptr[v];
    for (int j = c; j < cp; ++j) csr[base + j] = (unsigned short)N_NODES;
}

// ---------------- degree bucketing (R22) ----------------
__global__ void bucket_hist(const int* __restrict__ cnt, int* __restrict__ bcnt) {
    int v = blockIdx.x * 256 + threadIdx.x;
    if (v >= N_NODES) return;
    int b = min((cnt[v] + 7) >> 3, NBUCKET - 1);
    atomicAdd(&bcnt[b], 1);
}

__global__ void bucket_scan(const int* __restrict__ bcnt, int* __restrict__ boff2) {
    int t = threadIdx.x;   // 64 threads = 1 wave
    int raw = bcnt[t];
    int v = raw;
    for (int d = 1; d < 64; d <<= 1) {
        int u = __shfl_up(v, d);
        if (t >= d) v += u;
    }
    boff2[t] = v - raw;    // exclusive offsets
}

__global__ void bucket_scatter(const int* __restrict__ cnt, const int* __restrict__ boff2,
                               int* __restrict__ bcur, int* __restrict__ perm) {
    int v = blockIdx.x * 256 + threadIdx.x;
    if (v >= N_NODES) return;
    int b = min((cnt[v] + 7) >> 3, NBUCKET - 1);
    int pos = boff2[b] + atomicAdd(&bcur[b], 1);
    perm[pos] = v;
}

// repack conv_w into B-fragment order (fp16), zero ws accumulators, zero the
// 8 dummy node records in hwh2.
__global__ void wpack_zero_kernel(const float* __restrict__ W, _Float16* __restrict__ wpack,
                                  float* __restrict__ zreg, _Float16* __restrict__ hwh2) {
    int idx = blockIdx.x * 256 + threadIdx.x;
    if (idx < 4 * 4096) {
        int e = idx & 4095;
        int j = e & 7;
        int lane = (e >> 3) & 63;
        int ntkh = e >> 9;
        int kh = ntkh >> 2, nt = ntkh & 3;
        int m = lane & 15, quad = lane >> 4;
        wpack[idx] = (_Float16)W[(idx >> 12) * 4096 + (kh * 32 + quad * 8 + j) * 64 + nt * 16 + m];
    }
    if (idx < 256) {
        hwh2[(size_t)(idx >> 5) * PSTRIDE + (size_t)N_NODES * 32 + (idx & 31)] = (_Float16)0.0f;
    }
    for (int i = idx; i < ZERO_FLOATS; i += gridDim.x * 256) zreg[i] = 0.0f;
}

// reduce 64 BN slices + gamma/beta -> bnss. 512 threads: 4 slice-groups x 128
// cols (su:0-63, sq:64-127), LDS combine, 16 serial loads/thread (was 64).
__global__ void bn_reduce(const float* __restrict__ bn, const float* __restrict__ gamma,
                          const float* __restrict__ beta, float* __restrict__ bnss) {
    __shared__ float part[4][128];
    __shared__ float tot[128];
    int t = threadIdx.x;
    int f = t & 127, q = t >> 7;
    float s = 0.0f;
#pragma unroll
    for (int i = 0; i < 16; ++i) s += bn[(q * 16 + i) * 128 + f];
    part[q][f] = s;
    __syncthreads();
    if (t < 128) tot[t] = part[0][t] + part[1][t] + part[2][t] + part[3][t];
    __syncthreads();
    if (t < 64) {
        float su = tot[t], sq = tot[64 + t];
        const float inv_n = 1.0f / (float)NTOT;
        float mu = su * inv_n;
        float var = sq * inv_n - mu * mu;
        float sc = gamma[t] * rsqrtf(var + BN_EPS);
        bnss[t] = sc;
        bnss[64 + t] = beta[t] - mu * sc;
    }
}

// ---------------- fused GEMM (MFMA, packed W) ----------------
// Writes hwh2[part][v][32] with dinv[v] folded in (part = p*2 + feature_half).
template <int LAYER0>
__global__ __launch_bounds__(256) void gemm_fused(const void* __restrict__ srcv,
        const int* __restrict__ mask, const float* __restrict__ bnss,
        const int* __restrict__ batch, const _Float16* __restrict__ wpack,
        const float* __restrict__ dinv, _Float16* __restrict__ hwh,
        float* __restrict__ pooled) {
    __shared__ _Float16 sAh[64 * SAH_STRIDE];
    __shared__ _Float16 sC[64 * SC_STRIDE];
    int tid = threadIdx.x;
    size_t rowbase = (size_t)blockIdx.x * 64;
    int lane = tid & 63;
    int wv = tid >> 6;
    // batch values for this wave's 16 pooled rows: wave-uniform scalar loads,
    // issued up-front so latency hides under A-staging + MFMA.
    int bg[16];
#pragma unroll
    for (int rr = 0; rr < 16; ++rr)
        bg[rr] = batch[(int)((rowbase + wv * 16 + rr) % N_NODES)];
    // B frags: coalesced f16x8 loads from packed W (16 KB, L2-hot)
    const f16x8* wp = (const f16x8*)wpack;
    f16x8 bfrag[2][4];
#pragma unroll
    for (int kh = 0; kh < 2; ++kh)
#pragma unroll
        for (int nt = 0; nt < 4; ++nt)
            bfrag[kh][nt] = wp[(kh * 4 + nt) * 64 + lane];
    // A staging (fp16): thread -> (row r0 + it*16, features f4..f4+3)
    int r0 = tid >> 4;
    int f4l = (tid & 15) * 4;
    float4 sc4, sh4;
    if (!LAYER0) {
        sc4 = *(const float4*)&bnss[f4l];
        sh4 = *(const float4*)&bnss[64 + f4l];
    }
#pragma unroll
    for (int it = 0; it < 4; ++it) {
        int r = r0 + it * 16;
        int grow = (int)rowbase + r;
        float4 val;
        if (LAYER0) {
            const float* src = (const float*)srcv;
            int p = grow / N_NODES, v = grow - p * N_NODES;
            if (mask[p * N_NODES + v]) {
                val = make_float4(0.f, 0.f, 0.f, 0.f);
            } else {
                val = *(const float4*)&src[(size_t)v * HDIM + f4l];
            }
        } else {
            const _Float16* src = (const _Float16*)srcv;
            half4 hv = *(const half4*)&src[(size_t)grow * HDIM + f4l];
            val.x = fmaxf((float)hv.x * sc4.x + sh4.x, 0.0f);
            val.y = fmaxf((float)hv.y * sc4.y + sh4.y, 0.0f);
            val.z = fmaxf((float)hv.z * sc4.z + sh4.z, 0.0f);
            val.w = fmaxf((float)hv.w * sc4.w + sh4.w, 0.0f);
        }
        half4 hv4 = {(_Float16)val.x, (_Float16)val.y, (_Float16)val.z, (_Float16)val.w};
        *(half4*)&sAh[r * SAH_STRIDE + f4l] = hv4;
    }
    __syncthreads();
    // MFMA: wave wv owns rows wv*16..wv*16+15; A-frag = one ds_read_b128 per kh
    int m = lane & 15;
    int quad = lane >> 4;
    f32x4 acc4[4];
#pragma unroll
    for (int nt = 0; nt < 4; ++nt) acc4[nt] = (f32x4){0.f, 0.f, 0.f, 0.f};
#pragma unroll
    for (int kh = 0; kh < 2; ++kh) {
        f16x8 a = *(const f16x8*)&sAh[(wv * 16 + m) * SAH_STRIDE + kh * 32 + quad * 8];
#pragma unroll
        for (int nt = 0; nt < 4; ++nt)
            acc4[nt] = __builtin_amdgcn_mfma_f32_16x16x32_f16(a, bfrag[kh][nt], acc4[nt], 0, 0, 0);
    }
    // C frag layout: col = nt*16+m, row(in 16-tile) = quad*4+reg -> stage to sC
    // with dinv[v] folded in (gather consumes dinv_s-scaled messages).
#pragma unroll
    for (int reg = 0; reg < 4; ++reg) {
        int crow = wv * 16 + quad * 4 + reg;
        int growc = (int)rowbase + crow;
        int vc = growc % N_NODES;
        float dsc = dinv[vc];
#pragma unroll
        for (int nt = 0; nt < 4; ++nt)
            sC[crow * SC_STRIDE + nt * 16 + m] = (_Float16)(acc4[nt][reg] * dsc);
    }
    __syncthreads();
    // coalesced store first: thread -> row tid>>2, 16B chunk (tid&3) into both
    // feature-half partitions (64B node granules, contiguous per part).
    {
        int r = tid >> 2, c = tid & 3;
        int grow = (int)rowbase + r;
        int p = grow / N_NODES, v = grow - p * N_NODES;
        _Float16* dst0 = &hwh[(size_t)(p * 2 + 0) * PSTRIDE + (size_t)v * 32];
        _Float16* dst1 = &hwh[(size_t)(p * 2 + 1) * PSTRIDE + (size_t)v * 32];
        *(f16x8*)&dst0[c * 8] = *(f16x8*)&sC[r * SC_STRIDE + c * 8];
        *(f16x8*)&dst1[c * 8] = *(f16x8*)&sC[r * SC_STRIDE + (c + 4) * 8];
    }
    // pooling last (overlaps store drain): wave pools its 16 rows from sAh
    {
        int f = lane;
        int curg = -1;
        float acc = 0.0f;
#pragma unroll
        for (int rr = 0; rr < 16; ++rr) {
            int g = bg[rr];
            if (g != curg) {
                if (curg >= 0) atomicAdd(&pooled[curg * HDIM + f], acc * (1.0f / P_PERT));
                curg = g;
                acc = 0.0f;
            }
            acc += (float)sAh[(wv * 16 + rr) * SAH_STRIDE + f];
        }
        atomicAdd(&pooled[curg * HDIM + f], acc * (1.0f / P_PERT));
    }
}

// ---------------- XCD-partitioned gather, degree-bucketed ----------------
// part = blockIdx&7 -> XCD. Node slots indirect through perm[] (degree-sorted)
// so each wave's 16 nodes need EQUAL iteration counts (no masked-lane waste).
// Inner loop identical to verified R20.
__global__ __launch_bounds__(256) void gather_bn(const _Float16* __restrict__ hwh2,
        const int* __restrict__ rowptr, const unsigned short* __restrict__ csr,
        const float* __restrict__ dinv, const float* __restrict__ b,
        const int* __restrict__ perm,
        _Float16* __restrict__ h, float* __restrict__ bn) {
    __shared__ float lsum[4][4][8];
    __shared__ float lssq[4][4][8];
    int tid = threadIdx.x;
    int lane = tid & 63;
    int wv = tid >> 6;
    int part = blockIdx.x & 7;          // -> XCD
    int grp = blockIdx.x >> 3;          // node group (64 slots per block)
    int p = part >> 1, fh = part & 1;
    int n16 = lane >> 2;                // node within wave (0..15)
    int f16 = lane & 3;                 // 16B chunk within 64B part record
    int slotv = grp * 64 + wv * 16 + n16;
    bool valid = slotv < N_NODES;
    int vp = valid ? perm[slotv] : N_NODES;   // dummy row: safe zero reads
    int kb = 0, ke = 0;
    float di = 0.0f;
    if (valid) { kb = rowptr[vp]; ke = rowptr[vp + 1]; di = dinv[vp]; }
    const _Float16* lsrc = hwh2 + (size_t)part * PSTRIDE + f16 * 8;  // lane base
    f16x8 sv = *(const f16x8*)&lsrc[(size_t)vp * 32];   // self term
    float acc[8];
#pragma unroll
    for (int j = 0; j < 8; ++j) acc[j] = 0.0f;
    u16x8 ci = {};
    if (kb < ke) ci = *(const u16x8*)&csr[kb];          // prefetched indices
    for (int k = kb; k < ke; k += 8) {
        u16x8 cin = {};
        if (k + 8 < ke) cin = *(const u16x8*)&csr[k + 8];   // next-iter prefetch
        f16x8 m0 = *(const f16x8*)&lsrc[(size_t)ci[0] * 32];
        f16x8 m1 = *(const f16x8*)&lsrc[(size_t)ci[1] * 32];
        f16x8 m2 = *(const f16x8*)&lsrc[(size_t)ci[2] * 32];
        f16x8 m3 = *(const f16x8*)&lsrc[(size_t)ci[3] * 32];
        f16x8 m4 = *(const f16x8*)&lsrc[(size_t)ci[4] * 32];
        f16x8 m5 = *(const f16x8*)&lsrc[(size_t)ci[5] * 32];
        f16x8 m6 = *(const f16x8*)&lsrc[(size_t)ci[6] * 32];
        f16x8 m7 = *(const f16x8*)&lsrc[(size_t)ci[7] * 32];
        // packed-fp16 tree (v_pk_add_f16), 3 rounding levels, then f32 fold
        f16x8 s = ((m0 + m1) + (m2 + m3)) + ((m4 + m5) + (m6 + m7));
#pragma unroll
        for (int j = 0; j < 8; ++j) acc[j] += (float)s[j];
        ci = cin;
    }
    float hv[8], qv[8];
    float4 b0 = *(const float4*)&b[fh * 32 + f16 * 8];
    float4 b1 = *(const float4*)&b[fh * 32 + f16 * 8 + 4];
    float bb[8] = {b0.x, b0.y, b0.z, b0.w, b1.x, b1.y, b1.z, b1.w};
#pragma unroll
    for (int j = 0; j < 8; ++j) {
        float x = valid ? fmaf(di, acc[j] + (float)sv[j], bb[j]) : 0.0f;
        hv[j] = x;
        qv[j] = x * x;
    }
    if (valid) {
        f16x8 hh;
#pragma unroll
        for (int j = 0; j < 8; ++j) hh[j] = (_Float16)hv[j];
        // nontemporal: consumed only by the next dispatch; keep hwh2 L2-resident
        __builtin_nontemporal_store(hh,
            (f16x8*)&h[((size_t)p * N_NODES + (size_t)vp) * HDIM + fh * 32 + f16 * 8]);
    }
    // reduce across the 16 nodes (lane bits 2..5); 16B chunk preserved
#pragma unroll
    for (int d = 4; d <= 32; d <<= 1) {
#pragma unroll
        for (int j = 0; j < 8; ++j) {
            hv[j] += __shfl_xor(hv[j], d);
            qv[j] += __shfl_xor(qv[j], d);
        }
    }
    if (lane < 4) {
#pragma unroll
        for (int j = 0; j < 8; ++j) {
            lsum[wv][f16][j] = hv[j];
            lssq[wv][f16][j] = qv[j];
        }
    }
    __syncthreads();
    if (tid < 32) {
        int q = tid >> 3, j = tid & 7;
        float s = lsum[0][q][j] + lsum[1][q][j] + lsum[2][q][j] + lsum[3][q][j];
        float qq = lssq[0][q][j] + lssq[1][q][j] + lssq[2][q][j] + lssq[3][q][j];
        float* bns = bn + (blockIdx.x & (BN_SLICES - 1)) * 128;
        int f = fh * 32 + q * 8 + j;
        atomicAdd(&bns[f], s);
        atomicAdd(&bns[64 + f], qq);
    }
}

// pool of last layer's activation. Block = 64 f x 4 subgroups; each thread
// walks 4 consecutive (sorted-batch) nodes, run-length accumulating by graph
// before the atomic -> ~4x fewer pooled atomics.
__global__ void final_pool(const _Float16* __restrict__ h, const float* __restrict__ bnss,
                           const int* __restrict__ batch, float* __restrict__ pooled) {
    int f = threadIdx.x & 63;
    int sg = threadIdx.x >> 6;              // 0..3
    int vb = blockIdx.x * 16 + sg * 4;      // 4 nodes per thread
    float sc = bnss[f], sh = bnss[64 + f];
    int curg = -1;
    float acc = 0.0f;
#pragma unroll
    for (int i = 0; i < 4; ++i) {
        int v = vb + i;
        if (v >= N_NODES) break;
        float s = 0.0f;
#pragma unroll
        for (int p = 0; p < P_PERT; ++p) {
            size_t idx = ((size_t)(p * N_NODES + v)) * HDIM + f;
            s += fmaxf((float)h[idx] * sc + sh, 0.0f);
        }
        int g = batch[v];
        if (g != curg) {
            if (curg >= 0) atomicAdd(&pooled[curg * HDIM + f], acc * (1.0f / P_PERT));
            curg = g;
            acc = 0.0f;
        }
        acc += s;
    }
    if (curg >= 0) atomicAdd(&pooled[curg * HDIM + f], acc * (1.0f / P_PERT));
}

// y[g][c] = sum_i pooled_i[g] @ fc_w[i][:,c] + fc_b[i][c]; out = log_softmax(y)
__global__ void head_kernel(const float* __restrict__ pooled, const float* __restrict__ fcw,
                            const float* __restrict__ fcb, float* __restrict__ out) {
    int g = blockIdx.x;
    __shared__ float y[NCLASS];
    __shared__ float lse;
    int c = threadIdx.x;
    if (c < NCLASS) {
        float acc = 0.0f;
        for (int i = 0; i < 5; ++i) {
            acc += fcb[i * NCLASS + c];
            const float* pr = &pooled[((size_t)i * NGRAPH + g) * HDIM];
            const float* w = &fcw[i * HDIM * NCLASS + c];
            for (int k = 0; k < HDIM; ++k) acc += pr[k] * w[k * NCLASS];
        }
        y[c] = acc;
    }
    __syncthreads();
    if (threadIdx.x == 0) {
        float m = y[0];
        for (int i = 1; i < NCLASS; ++i) m = fmaxf(m, y[i]);
        float s = 0.0f;
        for (int i = 0; i < NCLASS; ++i) s += expf(y[i] - m);
        lse = m + logf(s);
    }
    __syncthreads();
    if (c < NCLASS) out[g * NCLASS + c] = y[c] - lse;
}

// ---------------- launch ----------------
extern "C" void kernel_launch(void* const* d_in, const int* in_sizes, int n_in,
                              void* d_out, int out_size, void* d_ws, size_t ws_size,
                              hipStream_t stream) {
    const float* x      = (const float*)d_in[0];
    const int*   ei     = (const int*)d_in[1];
    const int*   batch  = (const int*)d_in[2];
    const int*   mask   = (const int*)d_in[3];
    const float* conv_w = (const float*)d_in[4];
    const float* conv_b = (const float*)d_in[5];
    const float* gamma  = (const float*)d_in[6];
    const float* beta   = (const float*)d_in[7];
    const float* fcw    = (const float*)d_in[8];
    const float* fcb    = (const float*)d_in[9];
    float* out = (float*)d_out;

    char* ws = (char*)d_ws;
    // --- contiguous zeroed region [0, 1188480) (ZERO_FLOATS*4) ---
    int*      cnt     = (int*)(ws + 0);             // N ints
    int*      bcnt    = (int*)(ws + 200000);        // 64 ints (zeroed)
    int*      bcur    = (int*)(ws + 200256);        // 64 ints (zeroed)
    int*      boff2   = (int*)(ws + 200512);        // 64 ints (scan output)
    float*    pooled  = (float*)(ws + 400000);      // 5*512*64 f -> ends 1055360
    float*    bn      = (float*)(ws + 1055360);     // 4*64*128 f -> ends 1186432
    float*    bnss    = (float*)(ws + 1186432);     // 4*128 f -> ends 1188480
    // --- rest; h/hwh 4096-aligned, csr 16B-aligned ---
    int*      rowptr  = (int*)(ws + 1188480);       // N+1 ints -> ends 1388484
    float*    dinv    = (float*)(ws + 1388484);     // N f -> ends 1588484
    unsigned short* csr = (unsigned short*)(ws + 1588496); // 1.2M u16 (padded) -> ends 3988496
    _Float16* h       = (_Float16*)(ws + 3989504);  // 4096-aligned; 25.6 MB
    _Float16* hwh     = (_Float16*)(ws + 29589504); // 4096-aligned; 8 x 50001-node parts
    int*      bsum    = (int*)(ws + 55190016);      // 256 ints
    int*      boff    = (int*)(ws + 55191040);      // 256 ints
    _Float16* wpack   = (_Float16*)(ws + 55192064); // 4*4096 fp16 (32 KB)
    int*      slot    = (int*)(ws + 55224832);      // E ints (3.2 MB) -> ends 58424832
    int*      perm    = (int*)(ws + 58424832);      // N ints (200 KB) -> ends 58624832

    wpack_zero_kernel<<<512, 256, 0, stream>>>(conv_w, wpack, (float*)ws, hwh);
    count_kernel<<<(N_EDGES + 255) / 256, 256, 0, stream>>>(ei, cnt, slot);
    bucket_hist<<<SCAN_BLOCKS, 256, 0, stream>>>(cnt, bcnt);
    scan_reduce<<<SCAN_BLOCKS, 256, 0, stream>>>(cnt, bsum, dinv);
    scan_tops<<<1, 256, 0, stream>>>(bsum, boff, rowptr);
    scan_write<<<SCAN_BLOCKS, 256, 0, stream>>>(cnt, boff, rowptr);
    bucket_scan<<<1, 64, 0, stream>>>(bcnt, boff2);
    bucket_scatter<<<SCAN_BLOCKS, 256, 0, stream>>>(cnt, boff2, bcur, perm);
    fill_kernel<<<(N_EDGES + 255) / 256, 256, 0, stream>>>(ei, rowptr, slot, csr);
    pad_kernel<<<SCAN_BLOCKS, 256, 0, stream>>>(cnt, rowptr, csr);

    for (int i = 0; i < 4; ++i) {
        float* bni = bn + i * BN_SLICES * 128;
        if (i == 0)
            gemm_fused<1><<<NTOT / 64, 256, 0, stream>>>(x, mask, nullptr,
                                                         batch, wpack, dinv, hwh, pooled);
        else
            gemm_fused<0><<<NTOT / 64, 256, 0, stream>>>(h, nullptr, bnss + (i - 1) * 128,
                                                         batch, wpack + (size_t)i * 4096,
                                                         dinv, hwh,
                                                         pooled + (size_t)i * NGRAPH * HDIM);
        gather_bn<<<GATHER_BLOCKS, 256, 0, stream>>>(hwh, rowptr, csr, dinv,
                                                     conv_b + i * HDIM, perm, h, bni);
        bn_reduce<<<1, 512, 0, stream>>>(bni, gamma + i * HDIM, beta + i * HDIM,
                                         bnss + i * 128);
    }
    final_pool<<<(N_NODES + 15) / 16, 256, 0, stream>>>(
        h, bnss + 3 * 128, batch, pooled + (size_t)4 * NGRAPH * HDIM);
    head_kernel<<<NGRAPH, 64, 0, stream>>>(pooled, fcw, fcb, out);
}

// Round 20
// 415.768 us; speedup vs baseline: 2.8377x; 2.8377x over previous
//
#include <hip/hip_runtime.h>

// ---------------- problem constants ----------------
#define N_NODES 50000
#define N_EDGES 800000
#define P_PERT  4
#define NTOT    (P_PERT * N_NODES)   // 200000
#define HDIM    64
#define NGRAPH  512
#define NCLASS  10
#define BN_EPS  1e-5f
#define SCAN_BLOCKS ((N_NODES + 255) / 256)   // 196
#define BN_SLICES 64
#define NBUCKET 64
#define SAH_STRIDE 72  // halves; 144B rows, 16B-aligned frag reads, 2-way bank alias max
#define SC_STRIDE 72   // halves
#define ZERO_FLOATS 297120          // 1188480 bytes zeroed at ws start
#define PSTRIDE ((size_t)(N_NODES + 1) * 32)   // halves per part (+1 zeroed dummy node)
#define GATHER_BLOCKS (((N_NODES + 63) / 64) * 8)  // 782 groups x 8 parts = 6256

typedef _Float16 half4 __attribute__((ext_vector_type(4)));
typedef _Float16 f16x8 __attribute__((ext_vector_type(8)));
typedef float    f32x4 __attribute__((ext_vector_type(4)));
typedef unsigned short u16x8 __attribute__((ext_vector_type(8)));

// R18 VERIFIED R3: 8 XCD-resident hwh partitions, FETCH 188 -> 20.6 MB.
// R19 VERIFIED R5: node-per-lane padded walk 105 -> 57.6 us.
// R20 VERIFIED R11: 16 nodes x 4 flanes, pk tree, csr prefetch -> 46 us.
// R21 VERIFIED R13: slot-split fill, wide bn_reduce, run-length final_pool
// -> 399.9 us; gather_bn (4x46 us) the only hot kernel.
// R22 FAILED R19: bucket_hist/scatter used 50k global atomics on ~3 hot
// addresses (Poisson16 -> buckets 1-3): 20.7ms + 377us, total 1179.8.
// Guideline-12 violation. R23 (this round): two-level histogram — LDS
// per-block hist, ONE global atomic per (block, nonempty bin) recording
// blkbase; scatter uses LDS-atomic intra-block rank + blkbase. Perm
// semantics identical; gather/gemm byte-identical to R21/R22.
// R17 lesson: NO device-scope fences in the gather (kills per-XCD L2).
// R13 lesson: 64B node granules, 4096-aligned bases.

// ---------------- CSR build ----------------

// counts AND records each edge's slot within its dst list (atomic return val)
__global__ void count_kernel(const int* __restrict__ ei, int* __restrict__ cnt,
                             int* __restrict__ slot) {
    int j = blockIdx.x * blockDim.x + threadIdx.x;
    if (j >= N_EDGES) return;
    slot[j] = atomicAdd(&cnt[ei[N_EDGES + j]], 1);
}

// scans PADDED counts ((cnt+7)&~7) so every node's list is a multiple of 8;
// dinv still uses the raw count.
__global__ void scan_reduce(const int* __restrict__ cnt, int* __restrict__ bsum,
                            float* __restrict__ dinv) {
    __shared__ int sdata[256];
    int i = blockIdx.x * 256 + threadIdx.x;
    int v = (i < N_NODES) ? cnt[i] : 0;
    if (i < N_NODES) dinv[i] = rsqrtf((float)v + 1.0f);
    sdata[threadIdx.x] = (v + 7) & ~7;
    __syncthreads();
    for (int off = 128; off > 0; off >>= 1) {
        if (threadIdx.x < off) sdata[threadIdx.x] += sdata[threadIdx.x + off];
        __syncthreads();
    }
    if (threadIdx.x == 0) bsum[blockIdx.x] = sdata[0];
}

__global__ void scan_tops(const int* __restrict__ bsum, int* __restrict__ boff,
                          int* __restrict__ rowptr) {
    __shared__ int sdata[256];
    int t = threadIdx.x;
    int v = (t < SCAN_BLOCKS) ? bsum[t] : 0;
    sdata[t] = v;
    __syncthreads();
    for (int off = 1; off < 256; off <<= 1) {
        int tmp = (t >= off) ? sdata[t - off] : 0;
        __syncthreads();
        sdata[t] += tmp;
        __syncthreads();
    }
    if (t < SCAN_BLOCKS) boff[t] = sdata[t] - v;
    if (t == 255) rowptr[N_NODES] = sdata[255];
}

__global__ void scan_write(const int* __restrict__ cnt, const int* __restrict__ boff,
                           int* __restrict__ rowptr) {
    __shared__ int sdata[256];
    int i = blockIdx.x * 256 + threadIdx.x;
    int v = (i < N_NODES) ? ((cnt[i] + 7) & ~7) : 0;
    sdata[threadIdx.x] = v;
    __syncthreads();
    for (int off = 1; off < 256; off <<= 1) {
        int tmp = (threadIdx.x >= off) ? sdata[threadIdx.x - off] : 0;
        __syncthreads();
        sdata[threadIdx.x] += tmp;
        __syncthreads();
    }
    if (i < N_NODES) rowptr[i] = boff[blockIdx.x] + sdata[threadIdx.x] - v;
}

// csr: src index only (ushort). Atomic-free: position from precomputed slot.
__global__ void fill_kernel(const int* __restrict__ ei, const int* __restrict__ rowptr,
                            const int* __restrict__ slot, unsigned short* __restrict__ csr) {
    int j = blockIdx.x * blockDim.x + threadIdx.x;
    if (j >= N_EDGES) return;
    int s = ei[j], d = ei[N_EDGES + j];
    csr[rowptr[d] + slot[j]] = (unsigned short)s;
}

// fill pad slots [cnt, (cnt+7)&~7) with the dummy node index (zeroed record)
__global__ void pad_kernel(const int* __restrict__ cnt, const int* __restrict__ rowptr,
                           unsigned short* __restrict__ csr) {
    int v = blockIdx.x * 256 + threadIdx.x;
    if (v >= N_NODES) return;
    int c = cnt[v], cp = (c + 7) & ~7, base = rowptr[v];
    for (int j = c; j < cp; ++j) csr[base + j] = (unsigned short)N_NODES;
}

// ---------------- degree bucketing (R23: two-level, contention-free) -------
// LDS per-block histogram; one global atomic per (block, nonempty bin),
// recording the returned base in blkbase[blk][bin].
__global__ void bucket_hist(const int* __restrict__ cnt, int* __restrict__ bcnt,
                            int* __restrict__ blkbase) {
    __shared__ int lh[NBUCKET];
    int t = threadIdx.x;
    if (t < NBUCKET) lh[t] = 0;
    __syncthreads();
    int v = blockIdx.x * 256 + t;
    if (v < N_NODES) {
        int b = min((cnt[v] + 7) >> 3, NBUCKET - 1);
        atomicAdd(&lh[b], 1);                        // LDS atomic (per-CU)
    }
    __syncthreads();
    if (t < NBUCKET && lh[t] > 0)
        blkbase[blockIdx.x * NBUCKET + t] = atomicAdd(&bcnt[t], lh[t]);
}

__global__ void bucket_scan(const int* __restrict__ bcnt, int* __restrict__ boff2) {
    int t = threadIdx.x;   // 64 threads = 1 wave
    int raw = bcnt[t];
    int v = raw;
    for (int d = 1; d < 64; d <<= 1) {
        int u = __shfl_up(v, d);
        if (t >= d) v += u;
    }
    boff2[t] = v - raw;    // exclusive offsets
}

// intra-block rank via LDS atomic; global position = bin base + block base + rank
__global__ void bucket_scatter(const int* __restrict__ cnt, const int* __restrict__ boff2,
                               const int* __restrict__ blkbase, int* __restrict__ perm) {
    __shared__ int lcur[NBUCKET];
    int t = threadIdx.x;
    if (t < NBUCKET) lcur[t] = 0;
    __syncthreads();
    int v = blockIdx.x * 256 + t;
    if (v >= N_NODES) return;
    int b = min((cnt[v] + 7) >> 3, NBUCKET - 1);
    int lr = atomicAdd(&lcur[b], 1);                 // LDS atomic (per-CU)
    perm[boff2[b] + blkbase[blockIdx.x * NBUCKET + b] + lr] = v;
}

// repack conv_w into B-fragment order (fp16), zero ws accumulators, zero the
// 8 dummy node records in hwh2.
__global__ void wpack_zero_kernel(const float* __restrict__ W, _Float16* __restrict__ wpack,
                                  float* __restrict__ zreg, _Float16* __restrict__ hwh2) {
    int idx = blockIdx.x * 256 + threadIdx.x;
    if (idx < 4 * 4096) {
        int e = idx & 4095;
        int j = e & 7;
        int lane = (e >> 3) & 63;
        int ntkh = e >> 9;
        int kh = ntkh >> 2, nt = ntkh & 3;
        int m = lane & 15, quad = lane >> 4;
        wpack[idx] = (_Float16)W[(idx >> 12) * 4096 + (kh * 32 + quad * 8 + j) * 64 + nt * 16 + m];
    }
    if (idx < 256) {
        hwh2[(size_t)(idx >> 5) * PSTRIDE + (size_t)N_NODES * 32 + (idx & 31)] = (_Float16)0.0f;
    }
    for (int i = idx; i < ZERO_FLOATS; i += gridDim.x * 256) zreg[i] = 0.0f;
}

// reduce 64 BN slices + gamma/beta -> bnss. 512 threads: 4 slice-groups x 128
// cols (su:0-63, sq:64-127), LDS combine, 16 serial loads/thread (was 64).
__global__ void bn_reduce(const float* __restrict__ bn, const float* __restrict__ gamma,
                          const float* __restrict__ beta, float* __restrict__ bnss) {
    __shared__ float part[4][128];
    __shared__ float tot[128];
    int t = threadIdx.x;
    int f = t & 127, q = t >> 7;
    float s = 0.0f;
#pragma unroll
    for (int i = 0; i < 16; ++i) s += bn[(q * 16 + i) * 128 + f];
    part[q][f] = s;
    __syncthreads();
    if (t < 128) tot[t] = part[0][t] + part[1][t] + part[2][t] + part[3][t];
    __syncthreads();
    if (t < 64) {
        float su = tot[t], sq = tot[64 + t];
        const float inv_n = 1.0f / (float)NTOT;
        float mu = su * inv_n;
        float var = sq * inv_n - mu * mu;
        float sc = gamma[t] * rsqrtf(var + BN_EPS);
        bnss[t] = sc;
        bnss[64 + t] = beta[t] - mu * sc;
    }
}

// ---------------- fused GEMM (MFMA, packed W) ----------------
// Writes hwh2[part][v][32] with dinv[v] folded in (part = p*2 + feature_half).
template <int LAYER0>
__global__ __launch_bounds__(256) void gemm_fused(const void* __restrict__ srcv,
        const int* __restrict__ mask, const float* __restrict__ bnss,
        const int* __restrict__ batch, const _Float16* __restrict__ wpack,
        const float* __restrict__ dinv, _Float16* __restrict__ hwh,
        float* __restrict__ pooled) {
    __shared__ _Float16 sAh[64 * SAH_STRIDE];
    __shared__ _Float16 sC[64 * SC_STRIDE];
    int tid = threadIdx.x;
    size_t rowbase = (size_t)blockIdx.x * 64;
    int lane = tid & 63;
    int wv = tid >> 6;
    // batch values for this wave's 16 pooled rows: wave-uniform scalar loads,
    // issued up-front so latency hides under A-staging + MFMA.
    int bg[16];
#pragma unroll
    for (int rr = 0; rr < 16; ++rr)
        bg[rr] = batch[(int)((rowbase + wv * 16 + rr) % N_NODES)];
    // B frags: coalesced f16x8 loads from packed W (16 KB, L2-hot)
    const f16x8* wp = (const f16x8*)wpack;
    f16x8 bfrag[2][4];
#pragma unroll
    for (int kh = 0; kh < 2; ++kh)
#pragma unroll
        for (int nt = 0; nt < 4; ++nt)
            bfrag[kh][nt] = wp[(kh * 4 + nt) * 64 + lane];
    // A staging (fp16): thread -> (row r0 + it*16, features f4..f4+3)
    int r0 = tid >> 4;
    int f4l = (tid & 15) * 4;
    float4 sc4, sh4;
    if (!LAYER0) {
        sc4 = *(const float4*)&bnss[f4l];
        sh4 = *(const float4*)&bnss[64 + f4l];
    }
#pragma unroll
    for (int it = 0; it < 4; ++it) {
        int r = r0 + it * 16;
        int grow = (int)rowbase + r;
        float4 val;
        if (LAYER0) {
            const float* src = (const float*)srcv;
            int p = grow / N_NODES, v = grow - p * N_NODES;
            if (mask[p * N_NODES + v]) {
                val = make_float4(0.f, 0.f, 0.f, 0.f);
            } else {
                val = *(const float4*)&src[(size_t)v * HDIM + f4l];
            }
        } else {
            const _Float16* src = (const _Float16*)srcv;
            half4 hv = *(const half4*)&src[(size_t)grow * HDIM + f4l];
            val.x = fmaxf((float)hv.x * sc4.x + sh4.x, 0.0f);
            val.y = fmaxf((float)hv.y * sc4.y + sh4.y, 0.0f);
            val.z = fmaxf((float)hv.z * sc4.z + sh4.z, 0.0f);
            val.w = fmaxf((float)hv.w * sc4.w + sh4.w, 0.0f);
        }
        half4 hv4 = {(_Float16)val.x, (_Float16)val.y, (_Float16)val.z, (_Float16)val.w};
        *(half4*)&sAh[r * SAH_STRIDE + f4l] = hv4;
    }
    __syncthreads();
    // MFMA: wave wv owns rows wv*16..wv*16+15; A-frag = one ds_read_b128 per kh
    int m = lane & 15;
    int quad = lane >> 4;
    f32x4 acc4[4];
#pragma unroll
    for (int nt = 0; nt < 4; ++nt) acc4[nt] = (f32x4){0.f, 0.f, 0.f, 0.f};
#pragma unroll
    for (int kh = 0; kh < 2; ++kh) {
        f16x8 a = *(const f16x8*)&sAh[(wv * 16 + m) * SAH_STRIDE + kh * 32 + quad * 8];
#pragma unroll
        for (int nt = 0; nt < 4; ++nt)
            acc4[nt] = __builtin_amdgcn_mfma_f32_16x16x32_f16(a, bfrag[kh][nt], acc4[nt], 0, 0, 0);
    }
    // C frag layout: col = nt*16+m, row(in 16-tile) = quad*4+reg -> stage to sC
    // with dinv[v] folded in (gather consumes dinv_s-scaled messages).
#pragma unroll
    for (int reg = 0; reg < 4; ++reg) {
        int crow = wv * 16 + quad * 4 + reg;
        int growc = (int)rowbase + crow;
        int vc = growc % N_NODES;
        float dsc = dinv[vc];
#pragma unroll
        for (int nt = 0; nt < 4; ++nt)
            sC[crow * SC_STRIDE + nt * 16 + m] = (_Float16)(acc4[nt][reg] * dsc);
    }
    __syncthreads();
    // coalesced store first: thread -> row tid>>2, 16B chunk (tid&3) into both
    // feature-half partitions (64B node granules, contiguous per part).
    {
        int r = tid >> 2, c = tid & 3;
        int grow = (int)rowbase + r;
        int p = grow / N_NODES, v = grow - p * N_NODES;
        _Float16* dst0 = &hwh[(size_t)(p * 2 + 0) * PSTRIDE + (size_t)v * 32];
        _Float16* dst1 = &hwh[(size_t)(p * 2 + 1) * PSTRIDE + (size_t)v * 32];
        *(f16x8*)&dst0[c * 8] = *(f16x8*)&sC[r * SC_STRIDE + c * 8];
        *(f16x8*)&dst1[c * 8] = *(f16x8*)&sC[r * SC_STRIDE + (c + 4) * 8];
    }
    // pooling last (overlaps store drain): wave pools its 16 rows from sAh
    {
        int f = lane;
        int curg = -1;
        float acc = 0.0f;
#pragma unroll
        for (int rr = 0; rr < 16; ++rr) {
            int g = bg[rr];
            if (g != curg) {
                if (curg >= 0) atomicAdd(&pooled[curg * HDIM + f], acc * (1.0f / P_PERT));
                curg = g;
                acc = 0.0f;
            }
            acc += (float)sAh[(wv * 16 + rr) * SAH_STRIDE + f];
        }
        atomicAdd(&pooled[curg * HDIM + f], acc * (1.0f / P_PERT));
    }
}

// ---------------- XCD-partitioned gather, degree-bucketed ----------------
// part = blockIdx&7 -> XCD. Node slots indirect through perm[] (degree-sorted)
// so each wave's 16 nodes need EQUAL iteration counts (no masked-lane waste).
// Inner loop identical to verified R20.
__global__ __launch_bounds__(256) void gather_bn(const _Float16* __restrict__ hwh2,
        const int* __restrict__ rowptr, const unsigned short* __restrict__ csr,
        const float* __restrict__ dinv, const float* __restrict__ b,
        const int* __restrict__ perm,
        _Float16* __restrict__ h, float* __restrict__ bn) {
    __shared__ float lsum[4][4][8];
    __shared__ float lssq[4][4][8];
    int tid = threadIdx.x;
    int lane = tid & 63;
    int wv = tid >> 6;
    int part = blockIdx.x & 7;          // -> XCD
    int grp = blockIdx.x >> 3;          // node group (64 slots per block)
    int p = part >> 1, fh = part & 1;
    int n16 = lane >> 2;                // node within wave (0..15)
    int f16 = lane & 3;                 // 16B chunk within 64B part record
    int slotv = grp * 64 + wv * 16 + n16;
    bool valid = slotv < N_NODES;
    int vp = valid ? perm[slotv] : N_NODES;   // dummy row: safe zero reads
    int kb = 0, ke = 0;
    float di = 0.0f;
    if (valid) { kb = rowptr[vp]; ke = rowptr[vp + 1]; di = dinv[vp]; }
    const _Float16* lsrc = hwh2 + (size_t)part * PSTRIDE + f16 * 8;  // lane base
    f16x8 sv = *(const f16x8*)&lsrc[(size_t)vp * 32];   // self term
    float acc[8];
#pragma unroll
    for (int j = 0; j < 8; ++j) acc[j] = 0.0f;
    u16x8 ci = {};
    if (kb < ke) ci = *(const u16x8*)&csr[kb];          // prefetched indices
    for (int k = kb; k < ke; k += 8) {
        u16x8 cin = {};
        if (k + 8 < ke) cin = *(const u16x8*)&csr[k + 8];   // next-iter prefetch
        f16x8 m0 = *(const f16x8*)&lsrc[(size_t)ci[0] * 32];
        f16x8 m1 = *(const f16x8*)&lsrc[(size_t)ci[1] * 32];
        f16x8 m2 = *(const f16x8*)&lsrc[(size_t)ci[2] * 32];
        f16x8 m3 = *(const f16x8*)&lsrc[(size_t)ci[3] * 32];
        f16x8 m4 = *(const f16x8*)&lsrc[(size_t)ci[4] * 32];
        f16x8 m5 = *(const f16x8*)&lsrc[(size_t)ci[5] * 32];
        f16x8 m6 = *(const f16x8*)&lsrc[(size_t)ci[6] * 32];
        f16x8 m7 = *(const f16x8*)&lsrc[(size_t)ci[7] * 32];
        // packed-fp16 tree (v_pk_add_f16), 3 rounding levels, then f32 fold
        f16x8 s = ((m0 + m1) + (m2 + m3)) + ((m4 + m5) + (m6 + m7));
#pragma unroll
        for (int j = 0; j < 8; ++j) acc[j] += (float)s[j];
        ci = cin;
    }
    float hv[8], qv[8];
    float4 b0 = *(const float4*)&b[fh * 32 + f16 * 8];
    float4 b1 = *(const float4*)&b[fh * 32 + f16 * 8 + 4];
    float bb[8] = {b0.x, b0.y, b0.z, b0.w, b1.x, b1.y, b1.z, b1.w};
#pragma unroll
    for (int j = 0; j < 8; ++j) {
        float x = valid ? fmaf(di, acc[j] + (float)sv[j], bb[j]) : 0.0f;
        hv[j] = x;
        qv[j] = x * x;
    }
    if (valid) {
        f16x8 hh;
#pragma unroll
        for (int j = 0; j < 8; ++j) hh[j] = (_Float16)hv[j];
        // nontemporal: consumed only by the next dispatch; keep hwh2 L2-resident
        __builtin_nontemporal_store(hh,
            (f16x8*)&h[((size_t)p * N_NODES + (size_t)vp) * HDIM + fh * 32 + f16 * 8]);
    }
    // reduce across the 16 nodes (lane bits 2..5); 16B chunk preserved
#pragma unroll
    for (int d = 4; d <= 32; d <<= 1) {
#pragma unroll
        for (int j = 0; j < 8; ++j) {
            hv[j] += __shfl_xor(hv[j], d);
            qv[j] += __shfl_xor(qv[j], d);
        }
    }
    if (lane < 4) {
#pragma unroll
        for (int j = 0; j < 8; ++j) {
            lsum[wv][f16][j] = hv[j];
            lssq[wv][f16][j] = qv[j];
        }
    }
    __syncthreads();
    if (tid < 32) {
        int q = tid >> 3, j = tid & 7;
        float s = lsum[0][q][j] + lsum[1][q][j] + lsum[2][q][j] + lsum[3][q][j];
        float qq = lssq[0][q][j] + lssq[1][q][j] + lssq[2][q][j] + lssq[3][q][j];
        float* bns = bn + (blockIdx.x & (BN_SLICES - 1)) * 128;
        int f = fh * 32 + q * 8 + j;
        atomicAdd(&bns[f], s);
        atomicAdd(&bns[64 + f], qq);
    }
}

// pool of last layer's activation. Block = 64 f x 4 subgroups; each thread
// walks 4 consecutive (sorted-batch) nodes, run-length accumulating by graph
// before the atomic -> ~4x fewer pooled atomics.
__global__ void final_pool(const _Float16* __restrict__ h, const float* __restrict__ bnss,
                           const int* __restrict__ batch, float* __restrict__ pooled) {
    int f = threadIdx.x & 63;
    int sg = threadIdx.x >> 6;              // 0..3
    int vb = blockIdx.x * 16 + sg * 4;      // 4 nodes per thread
    float sc = bnss[f], sh = bnss[64 + f];
    int curg = -1;
    float acc = 0.0f;
#pragma unroll
    for (int i = 0; i < 4; ++i) {
        int v = vb + i;
        if (v >= N_NODES) break;
        float s = 0.0f;
#pragma unroll
        for (int p = 0; p < P_PERT; ++p) {
            size_t idx = ((size_t)(p * N_NODES + v)) * HDIM + f;
            s += fmaxf((float)h[idx] * sc + sh, 0.0f);
        }
        int g = batch[v];
        if (g != curg) {
            if (curg >= 0) atomicAdd(&pooled[curg * HDIM + f], acc * (1.0f / P_PERT));
            curg = g;
            acc = 0.0f;
        }
        acc += s;
    }
    if (curg >= 0) atomicAdd(&pooled[curg * HDIM + f], acc * (1.0f / P_PERT));
}

// y[g][c] = sum_i pooled_i[g] @ fc_w[i][:,c] + fc_b[i][c]; out = log_softmax(y)
__global__ void head_kernel(const float* __restrict__ pooled, const float* __restrict__ fcw,
                            const float* __restrict__ fcb, float* __restrict__ out) {
    int g = blockIdx.x;
    __shared__ float y[NCLASS];
    __shared__ float lse;
    int c = threadIdx.x;
    if (c < NCLASS) {
        float acc = 0.0f;
        for (int i = 0; i < 5; ++i) {
            acc += fcb[i * NCLASS + c];
            const float* pr = &pooled[((size_t)i * NGRAPH + g) * HDIM];
            const float* w = &fcw[i * HDIM * NCLASS + c];
            for (int k = 0; k < HDIM; ++k) acc += pr[k] * w[k * NCLASS];
        }
        y[c] = acc;
    }
    __syncthreads();
    if (threadIdx.x == 0) {
        float m = y[0];
        for (int i = 1; i < NCLASS; ++i) m = fmaxf(m, y[i]);
        float s = 0.0f;
        for (int i = 0; i < NCLASS; ++i) s += expf(y[i] - m);
        lse = m + logf(s);
    }
    __syncthreads();
    if (c < NCLASS) out[g * NCLASS + c] = y[c] - lse;
}

// ---------------- launch ----------------
extern "C" void kernel_launch(void* const* d_in, const int* in_sizes, int n_in,
                              void* d_out, int out_size, void* d_ws, size_t ws_size,
                              hipStream_t stream) {
    const float* x      = (const float*)d_in[0];
    const int*   ei     = (const int*)d_in[1];
    const int*   batch  = (const int*)d_in[2];
    const int*   mask   = (const int*)d_in[3];
    const float* conv_w = (const float*)d_in[4];
    const float* conv_b = (const float*)d_in[5];
    const float* gamma  = (const float*)d_in[6];
    const float* beta   = (const float*)d_in[7];
    const float* fcw    = (const float*)d_in[8];
    const float* fcb    = (const float*)d_in[9];
    float* out = (float*)d_out;

    char* ws = (char*)d_ws;
    // --- contiguous zeroed region [0, 1188480) (ZERO_FLOATS*4) ---
    int*      cnt     = (int*)(ws + 0);             // N ints
    int*      bcnt    = (int*)(ws + 200000);        // 64 ints (zeroed)
    int*      boff2   = (int*)(ws + 200512);        // 64 ints (scan output)
    float*    pooled  = (float*)(ws + 400000);      // 5*512*64 f -> ends 1055360
    float*    bn      = (float*)(ws + 1055360);     // 4*64*128 f -> ends 1186432
    float*    bnss    = (float*)(ws + 1186432);     // 4*128 f -> ends 1188480
    // --- rest; h/hwh 4096-aligned, csr 16B-aligned ---
    int*      rowptr  = (int*)(ws + 1188480);       // N+1 ints -> ends 1388484
    float*    dinv    = (float*)(ws + 1388484);     // N f -> ends 1588484
    unsigned short* csr = (unsigned short*)(ws + 1588496); // 1.2M u16 (padded) -> ends 3988496
    _Float16* h       = (_Float16*)(ws + 3989504);  // 4096-aligned; 25.6 MB
    _Float16* hwh     = (_Float16*)(ws + 29589504); // 4096-aligned; 8 x 50001-node parts
    int*      bsum    = (int*)(ws + 55190016);      // 256 ints
    int*      boff    = (int*)(ws + 55191040);      // 256 ints
    _Float16* wpack   = (_Float16*)(ws + 55192064); // 4*4096 fp16 (32 KB)
    int*      slot    = (int*)(ws + 55224832);      // E ints (3.2 MB) -> ends 58424832
    int*      perm    = (int*)(ws + 58424832);      // N ints (200 KB) -> ends 58624832
    int*      blkbase = (int*)(ws + 58624832);      // 196*64 ints (50 KB) -> ends 58675008

    wpack_zero_kernel<<<512, 256, 0, stream>>>(conv_w, wpack, (float*)ws, hwh);
    count_kernel<<<(N_EDGES + 255) / 256, 256, 0, stream>>>(ei, cnt, slot);
    bucket_hist<<<SCAN_BLOCKS, 256, 0, stream>>>(cnt, bcnt, blkbase);
    scan_reduce<<<SCAN_BLOCKS, 256, 0, stream>>>(cnt, bsum, dinv);
    scan_tops<<<1, 256, 0, stream>>>(bsum, boff, rowptr);
    scan_write<<<SCAN_BLOCKS, 256, 0, stream>>>(cnt, boff, rowptr);
    bucket_scan<<<1, 64, 0, stream>>>(bcnt, boff2);
    bucket_scatter<<<SCAN_BLOCKS, 256, 0, stream>>>(cnt, boff2, blkbase, perm);
    fill_kernel<<<(N_EDGES + 255) / 256, 256, 0, stream>>>(ei, rowptr, slot, csr);
    pad_kernel<<<SCAN_BLOCKS, 256, 0, stream>>>(cnt, rowptr, csr);

    for (int i = 0; i < 4; ++i) {
        float* bni = bn + i * BN_SLICES * 128;
        if (i == 0)
            gemm_fused<1><<<NTOT / 64, 256, 0, stream>>>(x, mask, nullptr,
                                                         batch, wpack, dinv, hwh, pooled);
        else
            gemm_fused<0><<<NTOT / 64, 256, 0, stream>>>(h, nullptr, bnss + (i - 1) * 128,
                                                         batch, wpack + (size_t)i * 4096,
                                                         dinv, hwh,
                                                         pooled + (size_t)i * NGRAPH * HDIM);
        gather_bn<<<GATHER_BLOCKS, 256, 0, stream>>>(hwh, rowptr, csr, dinv,
                                                     conv_b + i * HDIM, perm, h, bni);
        bn_reduce<<<1, 512, 0, stream>>>(bni, gamma + i * HDIM, beta + i * HDIM,
                                         bnss + i * 128);
    }
    final_pool<<<(N_NODES + 15) / 16, 256, 0, stream>>>(
        h, bnss + 3 * 128, batch, pooled + (size_t)4 * NGRAPH * HDIM);
    head_kernel<<<NGRAPH, 64, 0, stream>>>(pooled, fcw, fcb, out);
}

// Round 21
// 411.961 us; speedup vs baseline: 2.8639x; 1.0092x over previous
//
#include <hip/hip_runtime.h>

// ---------------- problem constants ----------------
#define N_NODES 50000
#define N_EDGES 800000
#define P_PERT  4
#define NTOT    (P_PERT * N_NODES)   // 200000
#define HDIM    64
#define NGRAPH  512
#define NCLASS  10
#define BN_EPS  1e-5f
#define SCAN_BLOCKS ((N_NODES + 255) / 256)   // 196
#define BN_SLICES 64
#define SAH_STRIDE 72  // halves; 144B rows, 16B-aligned frag reads, 2-way bank alias max
#define SC_STRIDE 72   // halves
#define ZERO_FLOATS 297120          // 1188480 bytes zeroed at ws start
#define PSTRIDE ((size_t)(N_NODES + 1) * 32)   // halves per part (+1 zeroed dummy node)
#define GATHER_BLOCKS (((N_NODES + 63) / 64) * 8)  // 782 groups x 8 parts = 6256

typedef _Float16 half4 __attribute__((ext_vector_type(4)));
typedef _Float16 f16x8 __attribute__((ext_vector_type(8)));
typedef float    f32x4 __attribute__((ext_vector_type(4)));
typedef unsigned short u16x8 __attribute__((ext_vector_type(8)));

// R18 VERIFIED R3: 8 XCD-resident hwh partitions, FETCH 188 -> 20.6 MB.
// R19 VERIFIED R5: node-per-lane padded walk 105 -> 57.6 us.
// R20 VERIFIED R11: 16 nodes x 4 flanes, pk tree, csr prefetch -> 46 us.
// R21 VERIFIED R13: slot-split fill, wide bn_reduce, run-length final_pool
// -> 399.9 us; gather_bn (4x46 us) the only hot kernel.
// R22/R23 REFUTED R20: degree-bucket perm equalized iterations (VALU 35->28%)
// but scattered node locality (FETCH 22.4->38.7 MB); gather flat at 45.3,
// total 415.8. Divergence is NOT the binding constraint; gather is
// per-iteration latency-bound (VALU 28%, HBM 18%, occ 52%).
// R24 (this round): revert perm (contiguous nodes, locality back); pad edge
// lists to x16 and process 16 edges/iter (2 prefetched u16x8 + 16 independent
// b128 loads in flight/lane, was 8) -> iterations/node ~2.2 -> ~1.3, one L2
// latency amortized over 2x work. Two 8-msg fp16 trees + separate f32 folds
// (same rounding depth as verified R20).
// R17 lesson: NO device-scope fences in the gather (kills per-XCD L2).
// R13 lesson: 64B node granules, 4096-aligned bases.

// ---------------- CSR build ----------------

// counts AND records each edge's slot within its dst list (atomic return val)
__global__ void count_kernel(const int* __restrict__ ei, int* __restrict__ cnt,
                             int* __restrict__ slot) {
    int j = blockIdx.x * blockDim.x + threadIdx.x;
    if (j >= N_EDGES) return;
    slot[j] = atomicAdd(&cnt[ei[N_EDGES + j]], 1);
}

// scans PADDED counts ((cnt+15)&~15) so every node's list is a multiple of 16;
// dinv still uses the raw count.
__global__ void scan_reduce(const int* __restrict__ cnt, int* __restrict__ bsum,
                            float* __restrict__ dinv) {
    __shared__ int sdata[256];
    int i = blockIdx.x * 256 + threadIdx.x;
    int v = (i < N_NODES) ? cnt[i] : 0;
    if (i < N_NODES) dinv[i] = rsqrtf((float)v + 1.0f);
    sdata[threadIdx.x] = (v + 15) & ~15;
    __syncthreads();
    for (int off = 128; off > 0; off >>= 1) {
        if (threadIdx.x < off) sdata[threadIdx.x] += sdata[threadIdx.x + off];
        __syncthreads();
    }
    if (threadIdx.x == 0) bsum[blockIdx.x] = sdata[0];
}

__global__ void scan_tops(const int* __restrict__ bsum, int* __restrict__ boff,
                          int* __restrict__ rowptr) {
    __shared__ int sdata[256];
    int t = threadIdx.x;
    int v = (t < SCAN_BLOCKS) ? bsum[t] : 0;
    sdata[t] = v;
    __syncthreads();
    for (int off = 1; off < 256; off <<= 1) {
        int tmp = (t >= off) ? sdata[t - off] : 0;
        __syncthreads();
        sdata[t] += tmp;
        __syncthreads();
    }
    if (t < SCAN_BLOCKS) boff[t] = sdata[t] - v;
    if (t == 255) rowptr[N_NODES] = sdata[255];
}

__global__ void scan_write(const int* __restrict__ cnt, const int* __restrict__ boff,
                           int* __restrict__ rowptr) {
    __shared__ int sdata[256];
    int i = blockIdx.x * 256 + threadIdx.x;
    int v = (i < N_NODES) ? ((cnt[i] + 15) & ~15) : 0;
    sdata[threadIdx.x] = v;
    __syncthreads();
    for (int off = 1; off < 256; off <<= 1) {
        int tmp = (threadIdx.x >= off) ? sdata[threadIdx.x - off] : 0;
        __syncthreads();
        sdata[threadIdx.x] += tmp;
        __syncthreads();
    }
    if (i < N_NODES) rowptr[i] = boff[blockIdx.x] + sdata[threadIdx.x] - v;
}

// csr: src index only (ushort). Atomic-free: position from precomputed slot.
__global__ void fill_kernel(const int* __restrict__ ei, const int* __restrict__ rowptr,
                            const int* __restrict__ slot, unsigned short* __restrict__ csr) {
    int j = blockIdx.x * blockDim.x + threadIdx.x;
    if (j >= N_EDGES) return;
    int s = ei[j], d = ei[N_EDGES + j];
    csr[rowptr[d] + slot[j]] = (unsigned short)s;
}

// fill pad slots [cnt, (cnt+15)&~15) with the dummy node index (zeroed record)
__global__ void pad_kernel(const int* __restrict__ cnt, const int* __restrict__ rowptr,
                           unsigned short* __restrict__ csr) {
    int v = blockIdx.x * 256 + threadIdx.x;
    if (v >= N_NODES) return;
    int c = cnt[v], cp = (c + 15) & ~15, base = rowptr[v];
    for (int j = c; j < cp; ++j) csr[base + j] = (unsigned short)N_NODES;
}

// repack conv_w into B-fragment order (fp16), zero ws accumulators, zero the
// 8 dummy node records in hwh2.
__global__ void wpack_zero_kernel(const float* __restrict__ W, _Float16* __restrict__ wpack,
                                  float* __restrict__ zreg, _Float16* __restrict__ hwh2) {
    int idx = blockIdx.x * 256 + threadIdx.x;
    if (idx < 4 * 4096) {
        int e = idx & 4095;
        int j = e & 7;
        int lane = (e >> 3) & 63;
        int ntkh = e >> 9;
        int kh = ntkh >> 2, nt = ntkh & 3;
        int m = lane & 15, quad = lane >> 4;
        wpack[idx] = (_Float16)W[(idx >> 12) * 4096 + (kh * 32 + quad * 8 + j) * 64 + nt * 16 + m];
    }
    if (idx < 256) {
        hwh2[(size_t)(idx >> 5) * PSTRIDE + (size_t)N_NODES * 32 + (idx & 31)] = (_Float16)0.0f;
    }
    for (int i = idx; i < ZERO_FLOATS; i += gridDim.x * 256) zreg[i] = 0.0f;
}

// reduce 64 BN slices + gamma/beta -> bnss. 512 threads: 4 slice-groups x 128
// cols (su:0-63, sq:64-127), LDS combine, 16 serial loads/thread (was 64).
__global__ void bn_reduce(const float* __restrict__ bn, const float* __restrict__ gamma,
                          const float* __restrict__ beta, float* __restrict__ bnss) {
    __shared__ float part[4][128];
    __shared__ float tot[128];
    int t = threadIdx.x;
    int f = t & 127, q = t >> 7;
    float s = 0.0f;
#pragma unroll
    for (int i = 0; i < 16; ++i) s += bn[(q * 16 + i) * 128 + f];
    part[q][f] = s;
    __syncthreads();
    if (t < 128) tot[t] = part[0][t] + part[1][t] + part[2][t] + part[3][t];
    __syncthreads();
    if (t < 64) {
        float su = tot[t], sq = tot[64 + t];
        const float inv_n = 1.0f / (float)NTOT;
        float mu = su * inv_n;
        float var = sq * inv_n - mu * mu;
        float sc = gamma[t] * rsqrtf(var + BN_EPS);
        bnss[t] = sc;
        bnss[64 + t] = beta[t] - mu * sc;
    }
}

// ---------------- fused GEMM (MFMA, packed W) ----------------
// Writes hwh2[part][v][32] with dinv[v] folded in (part = p*2 + feature_half).
template <int LAYER0>
__global__ __launch_bounds__(256) void gemm_fused(const void* __restrict__ srcv,
        const int* __restrict__ mask, const float* __restrict__ bnss,
        const int* __restrict__ batch, const _Float16* __restrict__ wpack,
        const float* __restrict__ dinv, _Float16* __restrict__ hwh,
        float* __restrict__ pooled) {
    __shared__ _Float16 sAh[64 * SAH_STRIDE];
    __shared__ _Float16 sC[64 * SC_STRIDE];
    int tid = threadIdx.x;
    size_t rowbase = (size_t)blockIdx.x * 64;
    int lane = tid & 63;
    int wv = tid >> 6;
    // batch values for this wave's 16 pooled rows: wave-uniform scalar loads,
    // issued up-front so latency hides under A-staging + MFMA.
    int bg[16];
#pragma unroll
    for (int rr = 0; rr < 16; ++rr)
        bg[rr] = batch[(int)((rowbase + wv * 16 + rr) % N_NODES)];
    // B frags: coalesced f16x8 loads from packed W (16 KB, L2-hot)
    const f16x8* wp = (const f16x8*)wpack;
    f16x8 bfrag[2][4];
#pragma unroll
    for (int kh = 0; kh < 2; ++kh)
#pragma unroll
        for (int nt = 0; nt < 4; ++nt)
            bfrag[kh][nt] = wp[(kh * 4 + nt) * 64 + lane];
    // A staging (fp16): thread -> (row r0 + it*16, features f4..f4+3)
    int r0 = tid >> 4;
    int f4l = (tid & 15) * 4;
    float4 sc4, sh4;
    if (!LAYER0) {
        sc4 = *(const float4*)&bnss[f4l];
        sh4 = *(const float4*)&bnss[64 + f4l];
    }
#pragma unroll
    for (int it = 0; it < 4; ++it) {
        int r = r0 + it * 16;
        int grow = (int)rowbase + r;
        float4 val;
        if (LAYER0) {
            const float* src = (const float*)srcv;
            int p = grow / N_NODES, v = grow - p * N_NODES;
            if (mask[p * N_NODES + v]) {
                val = make_float4(0.f, 0.f, 0.f, 0.f);
            } else {
                val = *(const float4*)&src[(size_t)v * HDIM + f4l];
            }
        } else {
            const _Float16* src = (const _Float16*)srcv;
            half4 hv = *(const half4*)&src[(size_t)grow * HDIM + f4l];
            val.x = fmaxf((float)hv.x * sc4.x + sh4.x, 0.0f);
            val.y = fmaxf((float)hv.y * sc4.y + sh4.y, 0.0f);
            val.z = fmaxf((float)hv.z * sc4.z + sh4.z, 0.0f);
            val.w = fmaxf((float)hv.w * sc4.w + sh4.w, 0.0f);
        }
        half4 hv4 = {(_Float16)val.x, (_Float16)val.y, (_Float16)val.z, (_Float16)val.w};
        *(half4*)&sAh[r * SAH_STRIDE + f4l] = hv4;
    }
    __syncthreads();
    // MFMA: wave wv owns rows wv*16..wv*16+15; A-frag = one ds_read_b128 per kh
    int m = lane & 15;
    int quad = lane >> 4;
    f32x4 acc4[4];
#pragma unroll
    for (int nt = 0; nt < 4; ++nt) acc4[nt] = (f32x4){0.f, 0.f, 0.f, 0.f};
#pragma unroll
    for (int kh = 0; kh < 2; ++kh) {
        f16x8 a = *(const f16x8*)&sAh[(wv * 16 + m) * SAH_STRIDE + kh * 32 + quad * 8];
#pragma unroll
        for (int nt = 0; nt < 4; ++nt)
            acc4[nt] = __builtin_amdgcn_mfma_f32_16x16x32_f16(a, bfrag[kh][nt], acc4[nt], 0, 0, 0);
    }
    // C frag layout: col = nt*16+m, row(in 16-tile) = quad*4+reg -> stage to sC
    // with dinv[v] folded in (gather consumes dinv_s-scaled messages).
#pragma unroll
    for (int reg = 0; reg < 4; ++reg) {
        int crow = wv * 16 + quad * 4 + reg;
        int growc = (int)rowbase + crow;
        int vc = growc % N_NODES;
        float dsc = dinv[vc];
#pragma unroll
        for (int nt = 0; nt < 4; ++nt)
            sC[crow * SC_STRIDE + nt * 16 + m] = (_Float16)(acc4[nt][reg] * dsc);
    }
    __syncthreads();
    // coalesced store first: thread -> row tid>>2, 16B chunk (tid&3) into both
    // feature-half partitions (64B node granules, contiguous per part).
    {
        int r = tid >> 2, c = tid & 3;
        int grow = (int)rowbase + r;
        int p = grow / N_NODES, v = grow - p * N_NODES;
        _Float16* dst0 = &hwh[(size_t)(p * 2 + 0) * PSTRIDE + (size_t)v * 32];
        _Float16* dst1 = &hwh[(size_t)(p * 2 + 1) * PSTRIDE + (size_t)v * 32];
        *(f16x8*)&dst0[c * 8] = *(f16x8*)&sC[r * SC_STRIDE + c * 8];
        *(f16x8*)&dst1[c * 8] = *(f16x8*)&sC[r * SC_STRIDE + (c + 4) * 8];
    }
    // pooling last (overlaps store drain): wave pools its 16 rows from sAh
    {
        int f = lane;
        int curg = -1;
        float acc = 0.0f;
#pragma unroll
        for (int rr = 0; rr < 16; ++rr) {
            int g = bg[rr];
            if (g != curg) {
                if (curg >= 0) atomicAdd(&pooled[curg * HDIM + f], acc * (1.0f / P_PERT));
                curg = g;
                acc = 0.0f;
            }
            acc += (float)sAh[(wv * 16 + rr) * SAH_STRIDE + f];
        }
        atomicAdd(&pooled[curg * HDIM + f], acc * (1.0f / P_PERT));
    }
}

// ---------------- XCD-partitioned gather, 16 nodes x 4 flanes, 16 edges/iter
// part = blockIdx&7 -> XCD; contiguous node blocks (locality verified R21).
// Each lane owns 16 B of its node's 64 B part record. Per iteration: 2
// prefetched u16x8 index loads + 16 independent b128 message loads in flight
// -> one L2 latency amortized over 2x the work vs R20. Branchless via x16
// padding (dummy node). Two 8-msg fp16 trees + separate f32 folds.
__global__ __launch_bounds__(256) void gather_bn(const _Float16* __restrict__ hwh2,
        const int* __restrict__ rowptr, const unsigned short* __restrict__ csr,
        const float* __restrict__ dinv, const float* __restrict__ b,
        _Float16* __restrict__ h, float* __restrict__ bn) {
    __shared__ float lsum[4][4][8];
    __shared__ float lssq[4][4][8];
    int tid = threadIdx.x;
    int lane = tid & 63;
    int wv = tid >> 6;
    int part = blockIdx.x & 7;          // -> XCD
    int grp = blockIdx.x >> 3;          // node group (64 nodes per block)
    int p = part >> 1, fh = part & 1;
    int n16 = lane >> 2;                // node within wave (0..15)
    int f16 = lane & 3;                 // 16B chunk within 64B part record
    int v = grp * 64 + wv * 16 + n16;
    bool valid = v < N_NODES;
    int vv = valid ? v : N_NODES;       // dummy row: safe zero reads
    int kb = 0, ke = 0;
    float di = 0.0f;
    if (valid) { kb = rowptr[v]; ke = rowptr[v + 1]; di = dinv[v]; }
    const _Float16* lsrc = hwh2 + (size_t)part * PSTRIDE + f16 * 8;  // lane base
    f16x8 sv = *(const f16x8*)&lsrc[(size_t)vv * 32];   // self term
    float acc[8];
#pragma unroll
    for (int j = 0; j < 8; ++j) acc[j] = 0.0f;
    u16x8 ci0 = {}, ci1 = {};
    if (kb < ke) {
        ci0 = *(const u16x8*)&csr[kb];
        ci1 = *(const u16x8*)&csr[kb + 8];
    }
    for (int k = kb; k < ke; k += 16) {
        u16x8 cin0 = {}, cin1 = {};
        if (k + 16 < ke) {
            cin0 = *(const u16x8*)&csr[k + 16];      // next-iter prefetch
            cin1 = *(const u16x8*)&csr[k + 24];
        }
        f16x8 m0 = *(const f16x8*)&lsrc[(size_t)ci0[0] * 32];
        f16x8 m1 = *(const f16x8*)&lsrc[(size_t)ci0[1] * 32];
        f16x8 m2 = *(const f16x8*)&lsrc[(size_t)ci0[2] * 32];
        f16x8 m3 = *(const f16x8*)&lsrc[(size_t)ci0[3] * 32];
        f16x8 m4 = *(const f16x8*)&lsrc[(size_t)ci0[4] * 32];
        f16x8 m5 = *(const f16x8*)&lsrc[(size_t)ci0[5] * 32];
        f16x8 m6 = *(const f16x8*)&lsrc[(size_t)ci0[6] * 32];
        f16x8 m7 = *(const f16x8*)&lsrc[(size_t)ci0[7] * 32];
        f16x8 m8  = *(const f16x8*)&lsrc[(size_t)ci1[0] * 32];
        f16x8 m9  = *(const f16x8*)&lsrc[(size_t)ci1[1] * 32];
        f16x8 m10 = *(const f16x8*)&lsrc[(size_t)ci1[2] * 32];
        f16x8 m11 = *(const f16x8*)&lsrc[(size_t)ci1[3] * 32];
        f16x8 m12 = *(const f16x8*)&lsrc[(size_t)ci1[4] * 32];
        f16x8 m13 = *(const f16x8*)&lsrc[(size_t)ci1[5] * 32];
        f16x8 m14 = *(const f16x8*)&lsrc[(size_t)ci1[6] * 32];
        f16x8 m15 = *(const f16x8*)&lsrc[(size_t)ci1[7] * 32];
        // two packed-fp16 trees (3 rounding levels each, as verified R20),
        // folded to f32 separately (same precision structure)
        f16x8 sA = ((m0 + m1) + (m2 + m3)) + ((m4 + m5) + (m6 + m7));
        f16x8 sB = ((m8 + m9) + (m10 + m11)) + ((m12 + m13) + (m14 + m15));
#pragma unroll
        for (int j = 0; j < 8; ++j) acc[j] += (float)sA[j] + (float)sB[j];
        ci0 = cin0;
        ci1 = cin1;
    }
    float hv[8], qv[8];
    float4 b0 = *(const float4*)&b[fh * 32 + f16 * 8];
    float4 b1 = *(const float4*)&b[fh * 32 + f16 * 8 + 4];
    float bb[8] = {b0.x, b0.y, b0.z, b0.w, b1.x, b1.y, b1.z, b1.w};
#pragma unroll
    for (int j = 0; j < 8; ++j) {
        float x = valid ? fmaf(di, acc[j] + (float)sv[j], bb[j]) : 0.0f;
        hv[j] = x;
        qv[j] = x * x;
    }
    if (valid) {
        f16x8 hh;
#pragma unroll
        for (int j = 0; j < 8; ++j) hh[j] = (_Float16)hv[j];
        // nontemporal: consumed only by the next dispatch; keep hwh2 L2-resident
        __builtin_nontemporal_store(hh,
            (f16x8*)&h[((size_t)p * N_NODES + (size_t)v) * HDIM + fh * 32 + f16 * 8]);
    }
    // reduce across the 16 nodes (lane bits 2..5); 16B chunk preserved
#pragma unroll
    for (int d = 4; d <= 32; d <<= 1) {
#pragma unroll
        for (int j = 0; j < 8; ++j) {
            hv[j] += __shfl_xor(hv[j], d);
            qv[j] += __shfl_xor(qv[j], d);
        }
    }
    if (lane < 4) {
#pragma unroll
        for (int j = 0; j < 8; ++j) {
            lsum[wv][f16][j] = hv[j];
            lssq[wv][f16][j] = qv[j];
        }
    }
    __syncthreads();
    if (tid < 32) {
        int q = tid >> 3, j = tid & 7;
        float s = lsum[0][q][j] + lsum[1][q][j] + lsum[2][q][j] + lsum[3][q][j];
        float qq = lssq[0][q][j] + lssq[1][q][j] + lssq[2][q][j] + lssq[3][q][j];
        float* bns = bn + (blockIdx.x & (BN_SLICES - 1)) * 128;
        int f = fh * 32 + q * 8 + j;
        atomicAdd(&bns[f], s);
        atomicAdd(&bns[64 + f], qq);
    }
}

// pool of last layer's activation. Block = 64 f x 4 subgroups; each thread
// walks 4 consecutive (sorted-batch) nodes, run-length accumulating by graph
// before the atomic -> ~4x fewer pooled atomics.
__global__ void final_pool(const _Float16* __restrict__ h, const float* __restrict__ bnss,
                           const int* __restrict__ batch, float* __restrict__ pooled) {
    int f = threadIdx.x & 63;
    int sg = threadIdx.x >> 6;              // 0..3
    int vb = blockIdx.x * 16 + sg * 4;      // 4 nodes per thread
    float sc = bnss[f], sh = bnss[64 + f];
    int curg = -1;
    float acc = 0.0f;
#pragma unroll
    for (int i = 0; i < 4; ++i) {
        int v = vb + i;
        if (v >= N_NODES) break;
        float s = 0.0f;
#pragma unroll
        for (int p = 0; p < P_PERT; ++p) {
            size_t idx = ((size_t)(p * N_NODES + v)) * HDIM + f;
            s += fmaxf((float)h[idx] * sc + sh, 0.0f);
        }
        int g = batch[v];
        if (g != curg) {
            if (curg >= 0) atomicAdd(&pooled[curg * HDIM + f], acc * (1.0f / P_PERT));
            curg = g;
            acc = 0.0f;
        }
        acc += s;
    }
    if (curg >= 0) atomicAdd(&pooled[curg * HDIM + f], acc * (1.0f / P_PERT));
}

// y[g][c] = sum_i pooled_i[g] @ fc_w[i][:,c] + fc_b[i][c]; out = log_softmax(y)
__global__ void head_kernel(const float* __restrict__ pooled, const float* __restrict__ fcw,
                            const float* __restrict__ fcb, float* __restrict__ out) {
    int g = blockIdx.x;
    __shared__ float y[NCLASS];
    __shared__ float lse;
    int c = threadIdx.x;
    if (c < NCLASS) {
        float acc = 0.0f;
        for (int i = 0; i < 5; ++i) {
            acc += fcb[i * NCLASS + c];
            const float* pr = &pooled[((size_t)i * NGRAPH + g) * HDIM];
            const float* w = &fcw[i * HDIM * NCLASS + c];
            for (int k = 0; k < HDIM; ++k) acc += pr[k] * w[k * NCLASS];
        }
        y[c] = acc;
    }
    __syncthreads();
    if (threadIdx.x == 0) {
        float m = y[0];
        for (int i = 1; i < NCLASS; ++i) m = fmaxf(m, y[i]);
        float s = 0.0f;
        for (int i = 0; i < NCLASS; ++i) s += expf(y[i] - m);
        lse = m + logf(s);
    }
    __syncthreads();
    if (c < NCLASS) out[g * NCLASS + c] = y[c] - lse;
}

// ---------------- launch ----------------
extern "C" void kernel_launch(void* const* d_in, const int* in_sizes, int n_in,
                              void* d_out, int out_size, void* d_ws, size_t ws_size,
                              hipStream_t stream) {
    const float* x      = (const float*)d_in[0];
    const int*   ei     = (const int*)d_in[1];
    const int*   batch  = (const int*)d_in[2];
    const int*   mask   = (const int*)d_in[3];
    const float* conv_w = (const float*)d_in[4];
    const float* conv_b = (const float*)d_in[5];
    const float* gamma  = (const float*)d_in[6];
    const float* beta   = (const float*)d_in[7];
    const float* fcw    = (const float*)d_in[8];
    const float* fcb    = (const float*)d_in[9];
    float* out = (float*)d_out;

    char* ws = (char*)d_ws;
    // --- contiguous zeroed region [0, 1188480) (ZERO_FLOATS*4) ---
    int*      cnt     = (int*)(ws + 0);             // N ints
    // (ws+200000..400000: spare, kept zeroed)
    float*    pooled  = (float*)(ws + 400000);      // 5*512*64 f -> ends 1055360
    float*    bn      = (float*)(ws + 1055360);     // 4*64*128 f -> ends 1186432
    float*    bnss    = (float*)(ws + 1186432);     // 4*128 f -> ends 1188480
    // --- rest; h/hwh 4096-aligned, csr 16B-aligned ---
    int*      rowptr  = (int*)(ws + 1188480);       // N+1 ints -> ends 1388484
    float*    dinv    = (float*)(ws + 1388484);     // N f -> ends 1588484
    unsigned short* csr = (unsigned short*)(ws + 1588496); // 1.6M u16 (x16-padded) -> ends 4788496
    _Float16* h       = (_Float16*)(ws + 4792320);  // 4096-aligned; 25.6 MB -> ends 30392320
    _Float16* hwh     = (_Float16*)(ws + 30392320); // 4096-aligned; 8 x 50001-node parts -> 55992832
    int*      bsum    = (int*)(ws + 55992832);      // 256 ints
    int*      boff    = (int*)(ws + 55993856);      // 256 ints
    _Float16* wpack   = (_Float16*)(ws + 55994880); // 4*4096 fp16 (32 KB) -> 56027648
    int*      slot    = (int*)(ws + 56027648);      // E ints (3.2 MB) -> ends 59227648

    wpack_zero_kernel<<<512, 256, 0, stream>>>(conv_w, wpack, (float*)ws, hwh);
    count_kernel<<<(N_EDGES + 255) / 256, 256, 0, stream>>>(ei, cnt, slot);
    scan_reduce<<<SCAN_BLOCKS, 256, 0, stream>>>(cnt, bsum, dinv);
    scan_tops<<<1, 256, 0, stream>>>(bsum, boff, rowptr);
    scan_write<<<SCAN_BLOCKS, 256, 0, stream>>>(cnt, boff, rowptr);
    fill_kernel<<<(N_EDGES + 255) / 256, 256, 0, stream>>>(ei, rowptr, slot, csr);
    pad_kernel<<<SCAN_BLOCKS, 256, 0, stream>>>(cnt, rowptr, csr);

    for (int i = 0; i < 4; ++i) {
        float* bni = bn + i * BN_SLICES * 128;
        if (i == 0)
            gemm_fused<1><<<NTOT / 64, 256, 0, stream>>>(x, mask, nullptr,
                                                         batch, wpack, dinv, hwh, pooled);
        else
            gemm_fused<0><<<NTOT / 64, 256, 0, stream>>>(h, nullptr, bnss + (i - 1) * 128,
                                                         batch, wpack + (size_t)i * 4096,
                                                         dinv, hwh,
                                                         pooled + (size_t)i * NGRAPH * HDIM);
        gather_bn<<<GATHER_BLOCKS, 256, 0, stream>>>(hwh, rowptr, csr, dinv,
                                                     conv_b + i * HDIM, h, bni);
        bn_reduce<<<1, 512, 0, stream>>>(bni, gamma + i * HDIM, beta + i * HDIM,
                                         bnss + i * 128);
    }
    final_pool<<<(N_NODES + 15) / 16, 256, 0, stream>>>(
        h, bnss + 3 * 128, batch, pooled + (size_t)4 * NGRAPH * HDIM);
    head_kernel<<<NGRAPH, 64, 0, stream>>>(pooled, fcw, fcb, out);
}

// Round 22
// 398.280 us; speedup vs baseline: 2.9623x; 1.0344x over previous
//
#include <hip/hip_runtime.h>

// ---------------- problem constants ----------------
#define N_NODES 50000
#define N_EDGES 800000
#define P_PERT  4
#define NTOT    (P_PERT * N_NODES)   // 200000
#define HDIM    64
#define NGRAPH  512
#define NCLASS  10
#define BN_EPS  1e-5f
#define SCAN_BLOCKS ((N_NODES + 255) / 256)   // 196
#define BN_SLICES 64
#define SAH_STRIDE 72  // halves; 144B rows, 16B-aligned frag reads, 2-way bank alias max
#define SC_STRIDE 72   // halves
#define ZERO_FLOATS 297120          // 1188480 bytes zeroed at ws start
#define PSTRIDE ((size_t)(N_NODES + 1) * 32)   // halves per part (+1 zeroed dummy node)
#define GATHER_BLOCKS (((N_NODES + 63) / 64) * 8)  // 782 groups x 8 parts = 6256

typedef _Float16 half4 __attribute__((ext_vector_type(4)));
typedef _Float16 f16x8 __attribute__((ext_vector_type(8)));
typedef float    f32x4 __attribute__((ext_vector_type(4)));
typedef unsigned short u16x8 __attribute__((ext_vector_type(8)));

// R18 VERIFIED R3: 8 XCD-resident hwh partitions, FETCH 188 -> 20.6 MB.
// R19 VERIFIED R5: node-per-lane padded walk 105 -> 57.6 us.
// R20 VERIFIED R11: 16 nodes x 4 flanes, pk tree, csr prefetch -> 46 us.
// R21 VERIFIED R13: slot-split fill, wide bn_reduce, run-length final_pool
// -> 399.9 us (SESSION BEST); gather_bn (4x46 us) the only hot kernel.
// R22/R23 REFUTED R20: degree-bucket perm -> locality loss (FETCH +73%), flat.
// R24 REFUTED R21: x16 edge unroll -> VGPR 36->52, occ 52->34%, flat (47 us).
// CONCLUSION: gather pinned 45-47 us across 3 structural variants (MLP up /
// divergence down / locality preserved all trade against each other);
// latency-structural floor for this decomposition. R25: restore exact R21.
// R17 lesson: NO device-scope fences in the gather (kills per-XCD L2).
// R13 lesson: 64B node granules, 4096-aligned bases.

// ---------------- CSR build ----------------

// counts AND records each edge's slot within its dst list (atomic return val)
__global__ void count_kernel(const int* __restrict__ ei, int* __restrict__ cnt,
                             int* __restrict__ slot) {
    int j = blockIdx.x * blockDim.x + threadIdx.x;
    if (j >= N_EDGES) return;
    slot[j] = atomicAdd(&cnt[ei[N_EDGES + j]], 1);
}

// scans PADDED counts ((cnt+7)&~7) so every node's list is a multiple of 8;
// dinv still uses the raw count.
__global__ void scan_reduce(const int* __restrict__ cnt, int* __restrict__ bsum,
                            float* __restrict__ dinv) {
    __shared__ int sdata[256];
    int i = blockIdx.x * 256 + threadIdx.x;
    int v = (i < N_NODES) ? cnt[i] : 0;
    if (i < N_NODES) dinv[i] = rsqrtf((float)v + 1.0f);
    sdata[threadIdx.x] = (v + 7) & ~7;
    __syncthreads();
    for (int off = 128; off > 0; off >>= 1) {
        if (threadIdx.x < off) sdata[threadIdx.x] += sdata[threadIdx.x + off];
        __syncthreads();
    }
    if (threadIdx.x == 0) bsum[blockIdx.x] = sdata[0];
}

__global__ void scan_tops(const int* __restrict__ bsum, int* __restrict__ boff,
                          int* __restrict__ rowptr) {
    __shared__ int sdata[256];
    int t = threadIdx.x;
    int v = (t < SCAN_BLOCKS) ? bsum[t] : 0;
    sdata[t] = v;
    __syncthreads();
    for (int off = 1; off < 256; off <<= 1) {
        int tmp = (t >= off) ? sdata[t - off] : 0;
        __syncthreads();
        sdata[t] += tmp;
        __syncthreads();
    }
    if (t < SCAN_BLOCKS) boff[t] = sdata[t] - v;
    if (t == 255) rowptr[N_NODES] = sdata[255];
}

__global__ void scan_write(const int* __restrict__ cnt, const int* __restrict__ boff,
                           int* __restrict__ rowptr) {
    __shared__ int sdata[256];
    int i = blockIdx.x * 256 + threadIdx.x;
    int v = (i < N_NODES) ? ((cnt[i] + 7) & ~7) : 0;
    sdata[threadIdx.x] = v;
    __syncthreads();
    for (int off = 1; off < 256; off <<= 1) {
        int tmp = (threadIdx.x >= off) ? sdata[threadIdx.x - off] : 0;
        __syncthreads();
        sdata[threadIdx.x] += tmp;
        __syncthreads();
    }
    if (i < N_NODES) rowptr[i] = boff[blockIdx.x] + sdata[threadIdx.x] - v;
}

// csr: src index only (ushort). Atomic-free: position from precomputed slot.
__global__ void fill_kernel(const int* __restrict__ ei, const int* __restrict__ rowptr,
                            const int* __restrict__ slot, unsigned short* __restrict__ csr) {
    int j = blockIdx.x * blockDim.x + threadIdx.x;
    if (j >= N_EDGES) return;
    int s = ei[j], d = ei[N_EDGES + j];
    csr[rowptr[d] + slot[j]] = (unsigned short)s;
}

// fill pad slots [cnt, (cnt+7)&~7) with the dummy node index (zeroed record)
__global__ void pad_kernel(const int* __restrict__ cnt, const int* __restrict__ rowptr,
                           unsigned short* __restrict__ csr) {
    int v = blockIdx.x * 256 + threadIdx.x;
    if (v >= N_NODES) return;
    int c = cnt[v], cp = (c + 7) & ~7, base = rowptr[v];
    for (int j = c; j < cp; ++j) csr[base + j] = (unsigned short)N_NODES;
}

// repack conv_w into B-fragment order (fp16), zero ws accumulators, zero the
// 8 dummy node records in hwh2.
__global__ void wpack_zero_kernel(const float* __restrict__ W, _Float16* __restrict__ wpack,
                                  float* __restrict__ zreg, _Float16* __restrict__ hwh2) {
    int idx = blockIdx.x * 256 + threadIdx.x;
    if (idx < 4 * 4096) {
        int e = idx & 4095;
        int j = e & 7;
        int lane = (e >> 3) & 63;
        int ntkh = e >> 9;
        int kh = ntkh >> 2, nt = ntkh & 3;
        int m = lane & 15, quad = lane >> 4;
        wpack[idx] = (_Float16)W[(idx >> 12) * 4096 + (kh * 32 + quad * 8 + j) * 64 + nt * 16 + m];
    }
    if (idx < 256) {
        hwh2[(size_t)(idx >> 5) * PSTRIDE + (size_t)N_NODES * 32 + (idx & 31)] = (_Float16)0.0f;
    }
    for (int i = idx; i < ZERO_FLOATS; i += gridDim.x * 256) zreg[i] = 0.0f;
}

// reduce 64 BN slices + gamma/beta -> bnss. 512 threads: 4 slice-groups x 128
// cols (su:0-63, sq:64-127), LDS combine, 16 serial loads/thread (was 64).
__global__ void bn_reduce(const float* __restrict__ bn, const float* __restrict__ gamma,
                          const float* __restrict__ beta, float* __restrict__ bnss) {
    __shared__ float part[4][128];
    __shared__ float tot[128];
    int t = threadIdx.x;
    int f = t & 127, q = t >> 7;
    float s = 0.0f;
#pragma unroll
    for (int i = 0; i < 16; ++i) s += bn[(q * 16 + i) * 128 + f];
    part[q][f] = s;
    __syncthreads();
    if (t < 128) tot[t] = part[0][t] + part[1][t] + part[2][t] + part[3][t];
    __syncthreads();
    if (t < 64) {
        float su = tot[t], sq = tot[64 + t];
        const float inv_n = 1.0f / (float)NTOT;
        float mu = su * inv_n;
        float var = sq * inv_n - mu * mu;
        float sc = gamma[t] * rsqrtf(var + BN_EPS);
        bnss[t] = sc;
        bnss[64 + t] = beta[t] - mu * sc;
    }
}

// ---------------- fused GEMM (MFMA, packed W) ----------------
// Writes hwh2[part][v][32] with dinv[v] folded in (part = p*2 + feature_half).
template <int LAYER0>
__global__ __launch_bounds__(256) void gemm_fused(const void* __restrict__ srcv,
        const int* __restrict__ mask, const float* __restrict__ bnss,
        const int* __restrict__ batch, const _Float16* __restrict__ wpack,
        const float* __restrict__ dinv, _Float16* __restrict__ hwh,
        float* __restrict__ pooled) {
    __shared__ _Float16 sAh[64 * SAH_STRIDE];
    __shared__ _Float16 sC[64 * SC_STRIDE];
    int tid = threadIdx.x;
    size_t rowbase = (size_t)blockIdx.x * 64;
    int lane = tid & 63;
    int wv = tid >> 6;
    // batch values for this wave's 16 pooled rows: wave-uniform scalar loads,
    // issued up-front so latency hides under A-staging + MFMA.
    int bg[16];
#pragma unroll
    for (int rr = 0; rr < 16; ++rr)
        bg[rr] = batch[(int)((rowbase + wv * 16 + rr) % N_NODES)];
    // B frags: coalesced f16x8 loads from packed W (16 KB, L2-hot)
    const f16x8* wp = (const f16x8*)wpack;
    f16x8 bfrag[2][4];
#pragma unroll
    for (int kh = 0; kh < 2; ++kh)
#pragma unroll
        for (int nt = 0; nt < 4; ++nt)
            bfrag[kh][nt] = wp[(kh * 4 + nt) * 64 + lane];
    // A staging (fp16): thread -> (row r0 + it*16, features f4..f4+3)
    int r0 = tid >> 4;
    int f4l = (tid & 15) * 4;
    float4 sc4, sh4;
    if (!LAYER0) {
        sc4 = *(const float4*)&bnss[f4l];
        sh4 = *(const float4*)&bnss[64 + f4l];
    }
#pragma unroll
    for (int it = 0; it < 4; ++it) {
        int r = r0 + it * 16;
        int grow = (int)rowbase + r;
        float4 val;
        if (LAYER0) {
            const float* src = (const float*)srcv;
            int p = grow / N_NODES, v = grow - p * N_NODES;
            if (mask[p * N_NODES + v]) {
                val = make_float4(0.f, 0.f, 0.f, 0.f);
            } else {
                val = *(const float4*)&src[(size_t)v * HDIM + f4l];
            }
        } else {
            const _Float16* src = (const _Float16*)srcv;
            half4 hv = *(const half4*)&src[(size_t)grow * HDIM + f4l];
            val.x = fmaxf((float)hv.x * sc4.x + sh4.x, 0.0f);
            val.y = fmaxf((float)hv.y * sc4.y + sh4.y, 0.0f);
            val.z = fmaxf((float)hv.z * sc4.z + sh4.z, 0.0f);
            val.w = fmaxf((float)hv.w * sc4.w + sh4.w, 0.0f);
        }
        half4 hv4 = {(_Float16)val.x, (_Float16)val.y, (_Float16)val.z, (_Float16)val.w};
        *(half4*)&sAh[r * SAH_STRIDE + f4l] = hv4;
    }
    __syncthreads();
    // MFMA: wave wv owns rows wv*16..wv*16+15; A-frag = one ds_read_b128 per kh
    int m = lane & 15;
    int quad = lane >> 4;
    f32x4 acc4[4];
#pragma unroll
    for (int nt = 0; nt < 4; ++nt) acc4[nt] = (f32x4){0.f, 0.f, 0.f, 0.f};
#pragma unroll
    for (int kh = 0; kh < 2; ++kh) {
        f16x8 a = *(const f16x8*)&sAh[(wv * 16 + m) * SAH_STRIDE + kh * 32 + quad * 8];
#pragma unroll
        for (int nt = 0; nt < 4; ++nt)
            acc4[nt] = __builtin_amdgcn_mfma_f32_16x16x32_f16(a, bfrag[kh][nt], acc4[nt], 0, 0, 0);
    }
    // C frag layout: col = nt*16+m, row(in 16-tile) = quad*4+reg -> stage to sC
    // with dinv[v] folded in (gather consumes dinv_s-scaled messages).
#pragma unroll
    for (int reg = 0; reg < 4; ++reg) {
        int crow = wv * 16 + quad * 4 + reg;
        int growc = (int)rowbase + crow;
        int vc = growc % N_NODES;
        float dsc = dinv[vc];
#pragma unroll
        for (int nt = 0; nt < 4; ++nt)
            sC[crow * SC_STRIDE + nt * 16 + m] = (_Float16)(acc4[nt][reg] * dsc);
    }
    __syncthreads();
    // coalesced store first: thread -> row tid>>2, 16B chunk (tid&3) into both
    // feature-half partitions (64B node granules, contiguous per part).
    {
        int r = tid >> 2, c = tid & 3;
        int grow = (int)rowbase + r;
        int p = grow / N_NODES, v = grow - p * N_NODES;
        _Float16* dst0 = &hwh[(size_t)(p * 2 + 0) * PSTRIDE + (size_t)v * 32];
        _Float16* dst1 = &hwh[(size_t)(p * 2 + 1) * PSTRIDE + (size_t)v * 32];
        *(f16x8*)&dst0[c * 8] = *(f16x8*)&sC[r * SC_STRIDE + c * 8];
        *(f16x8*)&dst1[c * 8] = *(f16x8*)&sC[r * SC_STRIDE + (c + 4) * 8];
    }
    // pooling last (overlaps store drain): wave pools its 16 rows from sAh
    {
        int f = lane;
        int curg = -1;
        float acc = 0.0f;
#pragma unroll
        for (int rr = 0; rr < 16; ++rr) {
            int g = bg[rr];
            if (g != curg) {
                if (curg >= 0) atomicAdd(&pooled[curg * HDIM + f], acc * (1.0f / P_PERT));
                curg = g;
                acc = 0.0f;
            }
            acc += (float)sAh[(wv * 16 + rr) * SAH_STRIDE + f];
        }
        atomicAdd(&pooled[curg * HDIM + f], acc * (1.0f / P_PERT));
    }
}

// ---------------- XCD-partitioned gather, 16 nodes x 4 flanes ----------------
// part = blockIdx&7 -> XCD. Each lane owns 16 B (f16x8) of its node's 64 B part
// record. 8 edges/iter: prefetched u16x8 csr index + 8 b128 message loads ->
// packed-fp16 tree-sum -> one f32 fold. Branchless via x8 padding (dummy node).
// (VERIFIED 46 us @ 36 VGPR / 52% occ — R24's x16 variant refuted at 34% occ.)
__global__ __launch_bounds__(256) void gather_bn(const _Float16* __restrict__ hwh2,
        const int* __restrict__ rowptr, const unsigned short* __restrict__ csr,
        const float* __restrict__ dinv, const float* __restrict__ b,
        _Float16* __restrict__ h, float* __restrict__ bn) {
    __shared__ float lsum[4][4][8];
    __shared__ float lssq[4][4][8];
    int tid = threadIdx.x;
    int lane = tid & 63;
    int wv = tid >> 6;
    int part = blockIdx.x & 7;          // -> XCD
    int grp = blockIdx.x >> 3;          // node group (64 nodes per block)
    int p = part >> 1, fh = part & 1;
    int n16 = lane >> 2;                // node within wave (0..15)
    int f16 = lane & 3;                 // 16B chunk within 64B part record
    int v = grp * 64 + wv * 16 + n16;
    bool valid = v < N_NODES;
    int vv = valid ? v : N_NODES;       // dummy row: safe zero reads
    int kb = 0, ke = 0;
    float di = 0.0f;
    if (valid) { kb = rowptr[v]; ke = rowptr[v + 1]; di = dinv[v]; }
    const _Float16* lsrc = hwh2 + (size_t)part * PSTRIDE + f16 * 8;  // lane base
    f16x8 sv = *(const f16x8*)&lsrc[(size_t)vv * 32];   // self term
    float acc[8];
#pragma unroll
    for (int j = 0; j < 8; ++j) acc[j] = 0.0f;
    u16x8 ci = {};
    if (kb < ke) ci = *(const u16x8*)&csr[kb];          // prefetched indices
    for (int k = kb; k < ke; k += 8) {
        u16x8 cin = {};
        if (k + 8 < ke) cin = *(const u16x8*)&csr[k + 8];   // next-iter prefetch
        f16x8 m0 = *(const f16x8*)&lsrc[(size_t)ci[0] * 32];
        f16x8 m1 = *(const f16x8*)&lsrc[(size_t)ci[1] * 32];
        f16x8 m2 = *(const f16x8*)&lsrc[(size_t)ci[2] * 32];
        f16x8 m3 = *(const f16x8*)&lsrc[(size_t)ci[3] * 32];
        f16x8 m4 = *(const f16x8*)&lsrc[(size_t)ci[4] * 32];
        f16x8 m5 = *(const f16x8*)&lsrc[(size_t)ci[5] * 32];
        f16x8 m6 = *(const f16x8*)&lsrc[(size_t)ci[6] * 32];
        f16x8 m7 = *(const f16x8*)&lsrc[(size_t)ci[7] * 32];
        // packed-fp16 tree (v_pk_add_f16), 3 rounding levels, then f32 fold
        f16x8 s = ((m0 + m1) + (m2 + m3)) + ((m4 + m5) + (m6 + m7));
#pragma unroll
        for (int j = 0; j < 8; ++j) acc[j] += (float)s[j];
        ci = cin;
    }
    float hv[8], qv[8];
    float4 b0 = *(const float4*)&b[fh * 32 + f16 * 8];
    float4 b1 = *(const float4*)&b[fh * 32 + f16 * 8 + 4];
    float bb[8] = {b0.x, b0.y, b0.z, b0.w, b1.x, b1.y, b1.z, b1.w};
#pragma unroll
    for (int j = 0; j < 8; ++j) {
        float x = valid ? fmaf(di, acc[j] + (float)sv[j], bb[j]) : 0.0f;
        hv[j] = x;
        qv[j] = x * x;
    }
    if (valid) {
        f16x8 hh;
#pragma unroll
        for (int j = 0; j < 8; ++j) hh[j] = (_Float16)hv[j];
        // nontemporal: consumed only by the next dispatch; keep hwh2 L2-resident
        __builtin_nontemporal_store(hh,
            (f16x8*)&h[((size_t)p * N_NODES + (size_t)v) * HDIM + fh * 32 + f16 * 8]);
    }
    // reduce across the 16 nodes (lane bits 2..5); 16B chunk preserved
#pragma unroll
    for (int d = 4; d <= 32; d <<= 1) {
#pragma unroll
        for (int j = 0; j < 8; ++j) {
            hv[j] += __shfl_xor(hv[j], d);
            qv[j] += __shfl_xor(qv[j], d);
        }
    }
    if (lane < 4) {
#pragma unroll
        for (int j = 0; j < 8; ++j) {
            lsum[wv][f16][j] = hv[j];
            lssq[wv][f16][j] = qv[j];
        }
    }
    __syncthreads();
    if (tid < 32) {
        int q = tid >> 3, j = tid & 7;
        float s = lsum[0][q][j] + lsum[1][q][j] + lsum[2][q][j] + lsum[3][q][j];
        float qq = lssq[0][q][j] + lssq[1][q][j] + lssq[2][q][j] + lssq[3][q][j];
        float* bns = bn + (blockIdx.x & (BN_SLICES - 1)) * 128;
        int f = fh * 32 + q * 8 + j;
        atomicAdd(&bns[f], s);
        atomicAdd(&bns[64 + f], qq);
    }
}

// pool of last layer's activation. Block = 64 f x 4 subgroups; each thread
// walks 4 consecutive (sorted-batch) nodes, run-length accumulating by graph
// before the atomic -> ~4x fewer pooled atomics.
__global__ void final_pool(const _Float16* __restrict__ h, const float* __restrict__ bnss,
                           const int* __restrict__ batch, float* __restrict__ pooled) {
    int f = threadIdx.x & 63;
    int sg = threadIdx.x >> 6;              // 0..3
    int vb = blockIdx.x * 16 + sg * 4;      // 4 nodes per thread
    float sc = bnss[f], sh = bnss[64 + f];
    int curg = -1;
    float acc = 0.0f;
#pragma unroll
    for (int i = 0; i < 4; ++i) {
        int v = vb + i;
        if (v >= N_NODES) break;
        float s = 0.0f;
#pragma unroll
        for (int p = 0; p < P_PERT; ++p) {
            size_t idx = ((size_t)(p * N_NODES + v)) * HDIM + f;
            s += fmaxf((float)h[idx] * sc + sh, 0.0f);
        }
        int g = batch[v];
        if (g != curg) {
            if (curg >= 0) atomicAdd(&pooled[curg * HDIM + f], acc * (1.0f / P_PERT));
            curg = g;
            acc = 0.0f;
        }
        acc += s;
    }
    if (curg >= 0) atomicAdd(&pooled[curg * HDIM + f], acc * (1.0f / P_PERT));
}

// y[g][c] = sum_i pooled_i[g] @ fc_w[i][:,c] + fc_b[i][c]; out = log_softmax(y)
__global__ void head_kernel(const float* __restrict__ pooled, const float* __restrict__ fcw,
                            const float* __restrict__ fcb, float* __restrict__ out) {
    int g = blockIdx.x;
    __shared__ float y[NCLASS];
    __shared__ float lse;
    int c = threadIdx.x;
    if (c < NCLASS) {
        float acc = 0.0f;
        for (int i = 0; i < 5; ++i) {
            acc += fcb[i * NCLASS + c];
            const float* pr = &pooled[((size_t)i * NGRAPH + g) * HDIM];
            const float* w = &fcw[i * HDIM * NCLASS + c];
            for (int k = 0; k < HDIM; ++k) acc += pr[k] * w[k * NCLASS];
        }
        y[c] = acc;
    }
    __syncthreads();
    if (threadIdx.x == 0) {
        float m = y[0];
        for (int i = 1; i < NCLASS; ++i) m = fmaxf(m, y[i]);
        float s = 0.0f;
        for (int i = 0; i < NCLASS; ++i) s += expf(y[i] - m);
        lse = m + logf(s);
    }
    __syncthreads();
    if (c < NCLASS) out[g * NCLASS + c] = y[c] - lse;
}

// ---------------- launch ----------------
extern "C" void kernel_launch(void* const* d_in, const int* in_sizes, int n_in,
                              void* d_out, int out_size, void* d_ws, size_t ws_size,
                              hipStream_t stream) {
    const float* x      = (const float*)d_in[0];
    const int*   ei     = (const int*)d_in[1];
    const int*   batch  = (const int*)d_in[2];
    const int*   mask   = (const int*)d_in[3];
    const float* conv_w = (const float*)d_in[4];
    const float* conv_b = (const float*)d_in[5];
    const float* gamma  = (const float*)d_in[6];
    const float* beta   = (const float*)d_in[7];
    const float* fcw    = (const float*)d_in[8];
    const float* fcb    = (const float*)d_in[9];
    float* out = (float*)d_out;

    char* ws = (char*)d_ws;
    // --- contiguous zeroed region [0, 1188480) (ZERO_FLOATS*4) ---
    int*      cnt     = (int*)(ws + 0);             // N ints
    // (ws+200000..400000: spare, kept zeroed)
    float*    pooled  = (float*)(ws + 400000);      // 5*512*64 f -> ends 1055360
    float*    bn      = (float*)(ws + 1055360);     // 4*64*128 f -> ends 1186432
    float*    bnss    = (float*)(ws + 1186432);     // 4*128 f -> ends 1188480
    // --- rest; h/hwh 4096-aligned, csr 16B-aligned ---
    int*      rowptr  = (int*)(ws + 1188480);       // N+1 ints -> ends 1388484
    float*    dinv    = (float*)(ws + 1388484);     // N f -> ends 1588484
    unsigned short* csr = (unsigned short*)(ws + 1588496); // 1.2M u16 (padded) -> ends 3988496
    _Float16* h       = (_Float16*)(ws + 3989504);  // 4096-aligned; 25.6 MB
    _Float16* hwh     = (_Float16*)(ws + 29589504); // 4096-aligned; 8 x 50001-node parts
    int*      bsum    = (int*)(ws + 55190016);      // 256 ints
    int*      boff    = (int*)(ws + 55191040);      // 256 ints
    _Float16* wpack   = (_Float16*)(ws + 55192064); // 4*4096 fp16 (32 KB)
    int*      slot    = (int*)(ws + 55224832);      // E ints (3.2 MB) -> ends 58424832

    wpack_zero_kernel<<<512, 256, 0, stream>>>(conv_w, wpack, (float*)ws, hwh);
    count_kernel<<<(N_EDGES + 255) / 256, 256, 0, stream>>>(ei, cnt, slot);
    scan_reduce<<<SCAN_BLOCKS, 256, 0, stream>>>(cnt, bsum, dinv);
    scan_tops<<<1, 256, 0, stream>>>(bsum, boff, rowptr);
    scan_write<<<SCAN_BLOCKS, 256, 0, stream>>>(cnt, boff, rowptr);
    fill_kernel<<<(N_EDGES + 255) / 256, 256, 0, stream>>>(ei, rowptr, slot, csr);
    pad_kernel<<<SCAN_BLOCKS, 256, 0, stream>>>(cnt, rowptr, csr);

    for (int i = 0; i < 4; ++i) {
        float* bni = bn + i * BN_SLICES * 128;
        if (i == 0)
            gemm_fused<1><<<NTOT / 64, 256, 0, stream>>>(x, mask, nullptr,
                                                         batch, wpack, dinv, hwh, pooled);
        else
            gemm_fused<0><<<NTOT / 64, 256, 0, stream>>>(h, nullptr, bnss + (i - 1) * 128,
                                                         batch, wpack + (size_t)i * 4096,
                                                         dinv, hwh,
                                                         pooled + (size_t)i * NGRAPH * HDIM);
        gather_bn<<<GATHER_BLOCKS, 256, 0, stream>>>(hwh, rowptr, csr, dinv,
                                                     conv_b + i * HDIM, h, bni);
        bn_reduce<<<1, 512, 0, stream>>>(bni, gamma + i * HDIM, beta + i * HDIM,
                                         bnss + i * 128);
    }
    final_pool<<<(N_NODES + 15) / 16, 256, 0, stream>>>(
        h, bnss + 3 * 128, batch, pooled + (size_t)4 * NGRAPH * HDIM);
    head_kernel<<<NGRAPH, 64, 0, stream>>>(pooled, fcw, fcb, out);
}